// Round 1
// baseline (191.890 us; speedup 1.0000x reference)
//
#include <hip/hip_runtime.h>

// AdaptiveConv2d v2: hypernet writes weights in MFMA-fragment layout
// (A-frags go global->registers, no weight LDS, 1 barrier/block);
// x staged as transposed bf16 with XOR-swizzled 16B granules
// (conflict-free ds_write_b128 + ds_read_b128). Wave = 64co x 32px.

typedef __bf16 bf16;
typedef __bf16 bf16x8 __attribute__((ext_vector_type(8)));
typedef float f32x4 __attribute__((ext_vector_type(4)));

#define NB 16
#define CI 64
#define CO 64
#define HH 128
#define WW 128
#define TS 16
#define HALO 18           // TS + 2
#define NPL (HALO * HALO) // 324 halo pixels
#define NKW 36864         // CO*CI*9
#define NROWS 36928
#define WT2_BYTES ((size_t)NB * 9 * 4096 * 2) // 1,179,648

// ---------------- hypernetwork ----------------
// grid 145 x 256. Each thread owns one W2 row, loops the 16 samples.
// Kernel rows land in wt2 pre-swizzled for the conv A-fragment:
//   elem off = ((b*9+tap)*8 + g*2 + kh)*512 + (q*16+m)*8 + j
//   g=co>>4, m=co&15, kh=ci>>5, q=(ci>>3)&3, j=ci&7
// so conv lane l = q*16+m reads frag (g,kh) as one dwordx4 at base + l*16.
__global__ __launch_bounds__(256)
void hyper_kernel(const float* __restrict__ z, const float* __restrict__ W0,
                  const float* __restrict__ b0, const float* __restrict__ W1,
                  const float* __restrict__ b1, const float* __restrict__ W2,
                  const float* __restrict__ b2, bf16* __restrict__ wt2,
                  float* __restrict__ biases) {
  __shared__ float h1s[NB][30];
  const int tid = threadIdx.x;
  if (tid < NB) {
    float h0[20];
    #pragma unroll
    for (int i = 0; i < 20; ++i) {
      float s = b0[i];
      #pragma unroll
      for (int j = 0; j < 16; ++j) s += W0[i * 16 + j] * z[tid * 16 + j];
      h0[i] = fmaxf(s, 0.f);
    }
    #pragma unroll
    for (int i = 0; i < 30; ++i) {
      float s = b1[i];
      #pragma unroll
      for (int j = 0; j < 20; ++j) s += W1[i * 20 + j] * h0[j];
      h1s[tid][i] = fmaxf(s, 0.f);
    }
  }
  __syncthreads();
  const int r = blockIdx.x * 256 + tid;
  if (r >= NROWS) return;
  float w2r[30];
  #pragma unroll
  for (int j = 0; j < 30; ++j) w2r[j] = W2[r * 30 + j];
  const float bb = b2[r];
  const bool isk = r < NKW;
  size_t base = 0;
  if (isk) {
    const int co = r / 576;
    const int rem = r - co * 576;
    const int ci = rem / 9;
    const int tap = rem - ci * 9;
    const int g = co >> 4, mm = co & 15;
    const int kh = ci >> 5, qq = (ci >> 3) & 3, jj = ci & 7;
    base = (size_t)(tap * 8 + g * 2 + kh) * 512 + (size_t)(qq * 16 + mm) * 8 + jj;
  }
  for (int b = 0; b < NB; ++b) {
    float s = bb;
    #pragma unroll
    for (int j = 0; j < 30; ++j) s += w2r[j] * h1s[b][j];
    s = fmaxf(s, 0.f);
    if (isk)
      wt2[(size_t)b * (9 * 4096) + base] = (bf16)s;
    else
      biases[b * CO + (r - NKW)] = s;
  }
}

// ---------------- conv (implicit GEMM, bf16 MFMA) ----------------
// block: 512 thr = 8 waves, 1 sample x 16x16 tile x all 64 co.
// Wave wv: all 64 co, pixel rows {2wv, 2wv+1}. acc[4 co-groups][2 rows].
// xt LDS: 324 rows (halo pixels) x 128 B (64 ci bf16); granule g (16B = 8 ci)
// stored at g ^ (pl & 7)  ->  ds_read_b128 spreads 8 lanes/bank-quad (optimal).
// A-frags: global->reg per tap (L1-resident, 8x inter-wave reuse). ONE barrier.
__global__ __launch_bounds__(512, 4)
void conv_kernel(const float* __restrict__ x, const bf16* __restrict__ wt2,
                 const float* __restrict__ bias, float* __restrict__ out) {
  __shared__ __align__(16) bf16 xt[NPL * 64]; // 41472 B -> 2 blocks/CU

  const int b = blockIdx.z;
  const int x0 = blockIdx.x * TS;
  const int y0 = blockIdx.y * TS;
  const int tid = threadIdx.x;
  const int lane = tid & 63;
  const int wv = tid >> 6; // 0..7
  const int m = lane & 15;
  const int q = lane >> 4;

  // ---- stage x: fp32 NCHW -> bf16, ci-contiguous, swizzled b128 writes ----
  // item = pl*8 + cig: 8 ci per thread-item -> one ds_write_b128.
  for (int it = tid; it < NPL * 8; it += 512) {
    const int pl = it >> 3, cig = it & 7;
    const int py = (pl * 57) >> 10; // pl/18, exact for pl < 512
    const int px = pl - py * 18;
    const int gy = y0 + py - 1, gx = x0 + px - 1;
    const bool inb = ((unsigned)gy < (unsigned)HH) & ((unsigned)gx < (unsigned)WW);
    bf16x8 v8;
    #pragma unroll
    for (int j = 0; j < 8; ++j) v8[j] = (bf16)0.f;
    if (inb) {
      const float* src =
          x + ((size_t)(b * CI + cig * 8) << 14) + (size_t)(gy * WW + gx);
      #pragma unroll
      for (int j = 0; j < 8; ++j) v8[j] = (bf16)src[(size_t)j << 14];
    }
    *reinterpret_cast<bf16x8*>(reinterpret_cast<char*>(xt) + (pl << 7) +
                               ((cig ^ (pl & 7)) << 4)) = v8;
  }

  f32x4 acc[4][2];
  #pragma unroll
  for (int i = 0; i < 4; ++i) {
    acc[i][0] = (f32x4){0.f, 0.f, 0.f, 0.f};
    acc[i][1] = (f32x4){0.f, 0.f, 0.f, 0.f};
  }

  const char* wbase = (const char*)wt2 + (size_t)b * (9 * 8192) + lane * 16;
  const int ty0 = wv * 2;

  __syncthreads(); // the only barrier

  #pragma unroll 1
  for (int tap = 0; tap < 9; ++tap) {
    const char* wt_tap = wbase + tap * 8192;
    bf16x8 a[4][2];
    #pragma unroll
    for (int i = 0; i < 4; ++i)
      #pragma unroll
      for (int kh = 0; kh < 2; ++kh)
        a[i][kh] = *reinterpret_cast<const bf16x8*>(wt_tap + (i * 2 + kh) * 1024);
    const int dy = (tap * 11) >> 5; // tap/3
    const int dx = tap - dy * 3;
    const int plb = (ty0 + dy) * 18 + dx + m;
    __builtin_amdgcn_s_setprio(1);
    #pragma unroll
    for (int kh = 0; kh < 2; ++kh) {
      const int qk = q + kh * 4;
      #pragma unroll
      for (int j = 0; j < 2; ++j) {
        const int pl = plb + j * 18;
        const bf16x8 bv = *reinterpret_cast<const bf16x8*>(
            reinterpret_cast<const char*>(xt) + (pl << 7) +
            ((qk ^ (pl & 7)) << 4));
        #pragma unroll
        for (int i = 0; i < 4; ++i)
          acc[i][j] =
              __builtin_amdgcn_mfma_f32_16x16x32_bf16(a[i][kh], bv, acc[i][j], 0, 0, 0);
      }
    }
    __builtin_amdgcn_s_setprio(0);
  }

  // epilogue: D col = m (px), row = q*4+r (co in group); co = i*16 + q*4 + r
  const float* bp = bias + b * CO;
  float* ob = out + ((size_t)(b * CO) << 14) + (size_t)((y0 + ty0) * WW + x0 + m);
  #pragma unroll
  for (int i = 0; i < 4; ++i)
    #pragma unroll
    for (int j = 0; j < 2; ++j)
      #pragma unroll
      for (int r = 0; r < 4; ++r) {
        const int co = i * 16 + q * 4 + r;
        float v = acc[i][j][r] + bp[co];
        ob[((size_t)co << 14) + j * WW] = fmaxf(v, 0.f);
      }
}

extern "C" void kernel_launch(void* const* d_in, const int* in_sizes, int n_in,
                              void* d_out, int out_size, void* d_ws,
                              size_t ws_size, hipStream_t stream) {
  const float* x = (const float*)d_in[0];
  const float* z = (const float*)d_in[1];
  const float* W0 = (const float*)d_in[2];
  const float* b0 = (const float*)d_in[3];
  const float* W1 = (const float*)d_in[4];
  const float* b1 = (const float*)d_in[5];
  const float* W2 = (const float*)d_in[6];
  const float* b2 = (const float*)d_in[7];
  float* out = (float*)d_out;

  // ws: wt2 bf16 fragment-layout [16][9][8 frag][512] | biases f32 [16][64]
  bf16* wt2 = (bf16*)d_ws;
  float* biases = (float*)((char*)d_ws + WT2_BYTES);

  hipLaunchKernelGGL(hyper_kernel, dim3((NROWS + 255) / 256), dim3(256), 0,
                     stream, z, W0, b0, W1, b1, W2, b2, wt2, biases);
  hipLaunchKernelGGL(conv_kernel, dim3(WW / TS, HH / TS, NB), dim3(512), 0,
                     stream, x, wt2, biases, out);
}

// Round 2
// 183.668 us; speedup vs baseline: 1.0448x; 1.0448x over previous
//
#include <hip/hip_runtime.h>

// AdaptiveConv2d v3: v2 + (a) cig-major staging so global x reads are
// pixel-contiguous (coalesced) while keeping conflict-free swizzled
// b128 LDS writes, (b) double-buffered A-fragment prefetch across taps
// (tap0 loads issued before staging; tap t+1 loads overlap tap t MFMAs).

typedef __bf16 bf16;
typedef __bf16 bf16x8 __attribute__((ext_vector_type(8)));
typedef float f32x4 __attribute__((ext_vector_type(4)));

#define NB 16
#define CI 64
#define CO 64
#define HH 128
#define WW 128
#define TS 16
#define HALO 18           // TS + 2
#define NPL (HALO * HALO) // 324 halo pixels
#define NKW 36864         // CO*CI*9
#define NROWS 36928
#define WT2_BYTES ((size_t)NB * 9 * 4096 * 2) // 1,179,648

// ---------------- hypernetwork ----------------
// grid 145 x 256. Each thread owns one W2 row, loops the 16 samples.
// Kernel rows land in wt2 pre-swizzled for the conv A-fragment:
//   elem off = ((b*9+tap)*8 + g*2 + kh)*512 + (q*16+m)*8 + j
//   g=co>>4, m=co&15, kh=ci>>5, q=(ci>>3)&3, j=ci&7
// so conv lane l = q*16+m reads frag (g,kh) as one dwordx4 at base + l*16.
__global__ __launch_bounds__(256)
void hyper_kernel(const float* __restrict__ z, const float* __restrict__ W0,
                  const float* __restrict__ b0, const float* __restrict__ W1,
                  const float* __restrict__ b1, const float* __restrict__ W2,
                  const float* __restrict__ b2, bf16* __restrict__ wt2,
                  float* __restrict__ biases) {
  __shared__ float h1s[NB][30];
  const int tid = threadIdx.x;
  if (tid < NB) {
    float h0[20];
    #pragma unroll
    for (int i = 0; i < 20; ++i) {
      float s = b0[i];
      #pragma unroll
      for (int j = 0; j < 16; ++j) s += W0[i * 16 + j] * z[tid * 16 + j];
      h0[i] = fmaxf(s, 0.f);
    }
    #pragma unroll
    for (int i = 0; i < 30; ++i) {
      float s = b1[i];
      #pragma unroll
      for (int j = 0; j < 20; ++j) s += W1[i * 20 + j] * h0[j];
      h1s[tid][i] = fmaxf(s, 0.f);
    }
  }
  __syncthreads();
  const int r = blockIdx.x * 256 + tid;
  if (r >= NROWS) return;
  float w2r[30];
  #pragma unroll
  for (int j = 0; j < 30; ++j) w2r[j] = W2[r * 30 + j];
  const float bb = b2[r];
  const bool isk = r < NKW;
  size_t base = 0;
  if (isk) {
    const int co = r / 576;
    const int rem = r - co * 576;
    const int ci = rem / 9;
    const int tap = rem - ci * 9;
    const int g = co >> 4, mm = co & 15;
    const int kh = ci >> 5, qq = (ci >> 3) & 3, jj = ci & 7;
    base = (size_t)(tap * 8 + g * 2 + kh) * 512 + (size_t)(qq * 16 + mm) * 8 + jj;
  }
  for (int b = 0; b < NB; ++b) {
    float s = bb;
    #pragma unroll
    for (int j = 0; j < 30; ++j) s += w2r[j] * h1s[b][j];
    s = fmaxf(s, 0.f);
    if (isk)
      wt2[(size_t)b * (9 * 4096) + base] = (bf16)s;
    else
      biases[b * CO + (r - NKW)] = s;
  }
}

// ---------------- conv (implicit GEMM, bf16 MFMA) ----------------
// block: 512 thr = 8 waves, 1 sample x 16x16 tile x all 64 co.
// Wave wv: all 64 co, pixel rows {2wv, 2wv+1}. acc[4 co-groups][2 rows].
// xt LDS: 324 rows (halo pixels) x 128 B (64 ci bf16); granule g (16B = 8 ci)
// stored at g ^ (pl & 7) -> both ds_write_b128 and ds_read_b128 conflict-free.
// Staging: cig-major items -> adjacent lanes read adjacent px (coalesced).
// A-frags: global->reg, double-buffered across taps. ONE barrier.
__global__ __launch_bounds__(512, 4)
void conv_kernel(const float* __restrict__ x, const bf16* __restrict__ wt2,
                 const float* __restrict__ bias, float* __restrict__ out) {
  __shared__ __align__(16) bf16 xt[NPL * 64]; // 41472 B -> 3 blocks/CU

  const int b = blockIdx.z;
  const int x0 = blockIdx.x * TS;
  const int y0 = blockIdx.y * TS;
  const int tid = threadIdx.x;
  const int lane = tid & 63;
  const int wv = tid >> 6; // 0..7
  const int m = lane & 15;
  const int q = lane >> 4;

  const char* wbase = (const char*)wt2 + (size_t)b * (9 * 8192) + lane * 16;

  // ---- prefetch tap-0 A-fragments (latency hides under staging) ----
  bf16x8 abuf[2][4][2];
  #pragma unroll
  for (int i = 0; i < 4; ++i)
    #pragma unroll
    for (int kh = 0; kh < 2; ++kh)
      abuf[0][i][kh] =
          *reinterpret_cast<const bf16x8*>(wbase + (i * 2 + kh) * 1024);

  // ---- stage x: fp32 NCHW -> bf16, cig-major (coalesced px-minor loads),
  //      swizzled conflict-free ds_write_b128 ----
  for (int it = tid; it < NPL * 8; it += 512) {
    const int cig = ((it >> 2) * 810) >> 16; // it/324 (=floor((it>>2)/81))
    const int pl = it - cig * 324;
    const int py = (pl * 57) >> 10; // pl/18, exact for pl < 512
    const int px = pl - py * 18;
    const int gy = y0 + py - 1, gx = x0 + px - 1;
    const bool inb = ((unsigned)gy < (unsigned)HH) & ((unsigned)gx < (unsigned)WW);
    bf16x8 v8;
    #pragma unroll
    for (int j = 0; j < 8; ++j) v8[j] = (bf16)0.f;
    if (inb) {
      const float* src =
          x + ((size_t)(b * CI + cig * 8) << 14) + (size_t)(gy * WW + gx);
      #pragma unroll
      for (int j = 0; j < 8; ++j) v8[j] = (bf16)src[(size_t)j << 14];
    }
    *reinterpret_cast<bf16x8*>(reinterpret_cast<char*>(xt) + (pl << 7) +
                               ((cig ^ (pl & 7)) << 4)) = v8;
  }

  f32x4 acc[4][2];
  #pragma unroll
  for (int i = 0; i < 4; ++i) {
    acc[i][0] = (f32x4){0.f, 0.f, 0.f, 0.f};
    acc[i][1] = (f32x4){0.f, 0.f, 0.f, 0.f};
  }

  const int ty0 = wv * 2;

  __syncthreads(); // the only barrier

  #pragma unroll
  for (int tap = 0; tap < 9; ++tap) {
    const int cur = tap & 1, nxt = cur ^ 1; // compile-time after unroll
    if (tap < 8) { // prefetch next tap's A-frags; overlaps this tap's MFMAs
      const char* wt_n = wbase + (tap + 1) * 8192;
      #pragma unroll
      for (int i = 0; i < 4; ++i)
        #pragma unroll
        for (int kh = 0; kh < 2; ++kh)
          abuf[nxt][i][kh] =
              *reinterpret_cast<const bf16x8*>(wt_n + (i * 2 + kh) * 1024);
    }
    const int dy = (tap * 11) >> 5; // tap/3
    const int dx = tap - dy * 3;
    const int plb = (ty0 + dy) * 18 + dx + m;
    __builtin_amdgcn_s_setprio(1);
    #pragma unroll
    for (int kh = 0; kh < 2; ++kh) {
      const int qk = q + kh * 4;
      #pragma unroll
      for (int j = 0; j < 2; ++j) {
        const int pl = plb + j * 18;
        const bf16x8 bv = *reinterpret_cast<const bf16x8*>(
            reinterpret_cast<const char*>(xt) + (pl << 7) +
            ((qk ^ (pl & 7)) << 4));
        #pragma unroll
        for (int i = 0; i < 4; ++i)
          acc[i][j] = __builtin_amdgcn_mfma_f32_16x16x32_bf16(
              abuf[cur][i][kh], bv, acc[i][j], 0, 0, 0);
      }
    }
    __builtin_amdgcn_s_setprio(0);
  }

  // epilogue: D col = m (px), row = q*4+r (co in group); co = i*16 + q*4 + r
  const float* bp = bias + b * CO;
  float* ob = out + ((size_t)(b * CO) << 14) + (size_t)((y0 + ty0) * WW + x0 + m);
  #pragma unroll
  for (int i = 0; i < 4; ++i)
    #pragma unroll
    for (int j = 0; j < 2; ++j)
      #pragma unroll
      for (int r = 0; r < 4; ++r) {
        const int co = i * 16 + q * 4 + r;
        float v = acc[i][j][r] + bp[co];
        ob[((size_t)co << 14) + j * WW] = fmaxf(v, 0.f);
      }
}

extern "C" void kernel_launch(void* const* d_in, const int* in_sizes, int n_in,
                              void* d_out, int out_size, void* d_ws,
                              size_t ws_size, hipStream_t stream) {
  const float* x = (const float*)d_in[0];
  const float* z = (const float*)d_in[1];
  const float* W0 = (const float*)d_in[2];
  const float* b0 = (const float*)d_in[3];
  const float* W1 = (const float*)d_in[4];
  const float* b1 = (const float*)d_in[5];
  const float* W2 = (const float*)d_in[6];
  const float* b2 = (const float*)d_in[7];
  float* out = (float*)d_out;

  // ws: wt2 bf16 fragment-layout [16][9][8 frag][512] | biases f32 [16][64]
  bf16* wt2 = (bf16*)d_ws;
  float* biases = (float*)((char*)d_ws + WT2_BYTES);

  hipLaunchKernelGGL(hyper_kernel, dim3((NROWS + 255) / 256), dim3(256), 0,
                     stream, z, W0, b0, W1, b1, W2, b2, wt2, biases);
  hipLaunchKernelGGL(conv_kernel, dim3(WW / TS, HH / TS, NB), dim3(512), 0,
                     stream, x, wt2, biases, out);
}

// Round 3
// 179.365 us; speedup vs baseline: 1.0698x; 1.0240x over previous
//
#include <hip/hip_runtime.h>

// AdaptiveConv2d v4: v3 + (a) batched staging — all global x loads issued
// into registers before any convert/LDS-write (one latency exposure, ~40
// loads in flight/wave), (b) XCD-aware bijective block swizzle so each
// XCD owns 2 complete samples (weight re-reads + halo sectors hit L2).

typedef __bf16 bf16;
typedef __bf16 bf16x8 __attribute__((ext_vector_type(8)));
typedef float f32x4 __attribute__((ext_vector_type(4)));

#define NB 16
#define CI 64
#define CO 64
#define HH 128
#define WW 128
#define TS 16
#define HALO 18           // TS + 2
#define NPL (HALO * HALO) // 324 halo pixels
#define NKW 36864         // CO*CI*9
#define NROWS 36928
#define WT2_BYTES ((size_t)NB * 9 * 4096 * 2) // 1,179,648

// ---------------- hypernetwork ----------------
// grid 145 x 256. Each thread owns one W2 row, loops the 16 samples.
// Kernel rows land in wt2 pre-swizzled for the conv A-fragment:
//   elem off = ((b*9+tap)*8 + g*2 + kh)*512 + (q*16+m)*8 + j
//   g=co>>4, m=co&15, kh=ci>>5, q=(ci>>3)&3, j=ci&7
__global__ __launch_bounds__(256)
void hyper_kernel(const float* __restrict__ z, const float* __restrict__ W0,
                  const float* __restrict__ b0, const float* __restrict__ W1,
                  const float* __restrict__ b1, const float* __restrict__ W2,
                  const float* __restrict__ b2, bf16* __restrict__ wt2,
                  float* __restrict__ biases) {
  __shared__ float h1s[NB][30];
  const int tid = threadIdx.x;
  if (tid < NB) {
    float h0[20];
    #pragma unroll
    for (int i = 0; i < 20; ++i) {
      float s = b0[i];
      #pragma unroll
      for (int j = 0; j < 16; ++j) s += W0[i * 16 + j] * z[tid * 16 + j];
      h0[i] = fmaxf(s, 0.f);
    }
    #pragma unroll
    for (int i = 0; i < 30; ++i) {
      float s = b1[i];
      #pragma unroll
      for (int j = 0; j < 20; ++j) s += W1[i * 20 + j] * h0[j];
      h1s[tid][i] = fmaxf(s, 0.f);
    }
  }
  __syncthreads();
  const int r = blockIdx.x * 256 + tid;
  if (r >= NROWS) return;
  float w2r[30];
  #pragma unroll
  for (int j = 0; j < 30; ++j) w2r[j] = W2[r * 30 + j];
  const float bb = b2[r];
  const bool isk = r < NKW;
  size_t base = 0;
  if (isk) {
    const int co = r / 576;
    const int rem = r - co * 576;
    const int ci = rem / 9;
    const int tap = rem - ci * 9;
    const int g = co >> 4, mm = co & 15;
    const int kh = ci >> 5, qq = (ci >> 3) & 3, jj = ci & 7;
    base = (size_t)(tap * 8 + g * 2 + kh) * 512 + (size_t)(qq * 16 + mm) * 8 + jj;
  }
  for (int b = 0; b < NB; ++b) {
    float s = bb;
    #pragma unroll
    for (int j = 0; j < 30; ++j) s += w2r[j] * h1s[b][j];
    s = fmaxf(s, 0.f);
    if (isk)
      wt2[(size_t)b * (9 * 4096) + base] = (bf16)s;
    else
      biases[b * CO + (r - NKW)] = s;
  }
}

// ---------------- conv (implicit GEMM, bf16 MFMA) ----------------
// 1D grid 1024, XCD-swizzled: XCD k gets blocks 128k..128k+127 = samples
// {2k,2k+1} (weights + halo sectors L2-shared). Block: 512 thr = 8 waves,
// 1 sample x 16x16 tile x all 64 co. Wave wv: pixel rows {2wv, 2wv+1}.
// xt LDS: 324 px rows x 128 B (64 ci bf16); granule g at g^(pl&7) ->
// conflict-free b128 writes AND reads. Staging loads batch-issued into
// registers (single latency exposure). A-frags double-buffered across taps.
__global__ __launch_bounds__(512, 4)
void conv_kernel(const float* __restrict__ x, const bf16* __restrict__ wt2,
                 const float* __restrict__ bias, float* __restrict__ out) {
  __shared__ __align__(16) bf16 xt[NPL * 64]; // 41472 B

  const int id = (blockIdx.x & 7) * 128 + (blockIdx.x >> 3); // bijective
  const int b = id >> 6;
  const int x0 = (id & 7) * TS;
  const int y0 = ((id >> 3) & 7) * TS;

  const int tid = threadIdx.x;
  const int lane = tid & 63;
  const int wv = tid >> 6; // 0..7
  const int m = lane & 15;
  const int q = lane >> 4;

  const char* wbase = (const char*)wt2 + (size_t)b * (9 * 8192) + lane * 16;

  // ---- prefetch tap-0 A-fragments (first in the load queue) ----
  bf16x8 abuf[2][4][2];
  #pragma unroll
  for (int i = 0; i < 4; ++i)
    #pragma unroll
    for (int kh = 0; kh < 2; ++kh)
      abuf[0][i][kh] =
          *reinterpret_cast<const bf16x8*>(wbase + (i * 2 + kh) * 1024);

  // ---- phase 1: issue ALL staging loads (no waits between items) ----
  // item = cig*324 + pl (cig-major: lanes walk adjacent px -> coalesced).
  // OOB: clamp address (stays inside sample), zero via select after load.
  const float* xb = x + ((size_t)b << 20);
  float vbuf[6][8];
  int pls[6], cigs[6];
  bool inbs[6];
  #pragma unroll
  for (int t = 0; t < 6; ++t) {
    const int it = min(tid + t * 512, NPL * 8 - 1); // dup-clamp tail lanes
    const int cig = ((it >> 2) * 810) >> 16;        // it/324
    const int pl = it - cig * 324;
    const int py = (pl * 57) >> 10; // pl/18
    const int px = pl - py * 18;
    int gy = y0 + py - 1, gx = x0 + px - 1;
    inbs[t] = ((unsigned)gy < (unsigned)HH) & ((unsigned)gx < (unsigned)WW);
    gy = min(max(gy, 0), HH - 1);
    gx = min(max(gx, 0), WW - 1);
    pls[t] = pl;
    cigs[t] = cig;
    const float* src = xb + ((size_t)cig << 17) + (gy << 7) + gx;
    #pragma unroll
    for (int j = 0; j < 8; ++j) vbuf[t][j] = src[(size_t)j << 14];
  }

  // ---- phase 2: convert + swizzled conflict-free b128 writes ----
  #pragma unroll
  for (int t = 0; t < 6; ++t) {
    if (t == 5 && tid >= NPL * 8 - 5 * 512) break; // tail: only tid<32
    bf16x8 v8;
    #pragma unroll
    for (int j = 0; j < 8; ++j)
      v8[j] = inbs[t] ? (bf16)vbuf[t][j] : (bf16)0.f;
    *reinterpret_cast<bf16x8*>(reinterpret_cast<char*>(xt) + (pls[t] << 7) +
                               ((cigs[t] ^ (pls[t] & 7)) << 4)) = v8;
  }

  f32x4 acc[4][2];
  #pragma unroll
  for (int i = 0; i < 4; ++i) {
    acc[i][0] = (f32x4){0.f, 0.f, 0.f, 0.f};
    acc[i][1] = (f32x4){0.f, 0.f, 0.f, 0.f};
  }

  const int ty0 = wv * 2;

  __syncthreads(); // the only barrier

  #pragma unroll
  for (int tap = 0; tap < 9; ++tap) {
    const int cur = tap & 1, nxt = cur ^ 1; // compile-time after unroll
    if (tap < 8) { // prefetch next tap's A-frags; overlaps this tap's MFMAs
      const char* wt_n = wbase + (tap + 1) * 8192;
      #pragma unroll
      for (int i = 0; i < 4; ++i)
        #pragma unroll
        for (int kh = 0; kh < 2; ++kh)
          abuf[nxt][i][kh] =
              *reinterpret_cast<const bf16x8*>(wt_n + (i * 2 + kh) * 1024);
    }
    const int dy = (tap * 11) >> 5; // tap/3
    const int dx = tap - dy * 3;
    const int plb = (ty0 + dy) * 18 + dx + m;
    __builtin_amdgcn_s_setprio(1);
    #pragma unroll
    for (int kh = 0; kh < 2; ++kh) {
      const int qk = q + kh * 4;
      #pragma unroll
      for (int j = 0; j < 2; ++j) {
        const int pl = plb + j * 18;
        const bf16x8 bv = *reinterpret_cast<const bf16x8*>(
            reinterpret_cast<const char*>(xt) + (pl << 7) +
            ((qk ^ (pl & 7)) << 4));
        #pragma unroll
        for (int i = 0; i < 4; ++i)
          acc[i][j] = __builtin_amdgcn_mfma_f32_16x16x32_bf16(
              abuf[cur][i][kh], bv, acc[i][j], 0, 0, 0);
      }
    }
    __builtin_amdgcn_s_setprio(0);
  }

  // epilogue: D col = m (px), row = q*4+r (co in group); co = i*16 + q*4 + r
  const float* bp = bias + b * CO;
  float* ob = out + ((size_t)(b * CO) << 14) + (size_t)((y0 + ty0) * WW + x0 + m);
  #pragma unroll
  for (int i = 0; i < 4; ++i)
    #pragma unroll
    for (int j = 0; j < 2; ++j)
      #pragma unroll
      for (int r = 0; r < 4; ++r) {
        const int co = i * 16 + q * 4 + r;
        float v = acc[i][j][r] + bp[co];
        ob[((size_t)co << 14) + j * WW] = fmaxf(v, 0.f);
      }
}

extern "C" void kernel_launch(void* const* d_in, const int* in_sizes, int n_in,
                              void* d_out, int out_size, void* d_ws,
                              size_t ws_size, hipStream_t stream) {
  const float* x = (const float*)d_in[0];
  const float* z = (const float*)d_in[1];
  const float* W0 = (const float*)d_in[2];
  const float* b0 = (const float*)d_in[3];
  const float* W1 = (const float*)d_in[4];
  const float* b1 = (const float*)d_in[5];
  const float* W2 = (const float*)d_in[6];
  const float* b2 = (const float*)d_in[7];
  float* out = (float*)d_out;

  // ws: wt2 bf16 fragment-layout [16][9][8 frag][512] | biases f32 [16][64]
  bf16* wt2 = (bf16*)d_ws;
  float* biases = (float*)((char*)d_ws + WT2_BYTES);

  hipLaunchKernelGGL(hyper_kernel, dim3((NROWS + 255) / 256), dim3(256), 0,
                     stream, z, W0, b0, W1, b1, W2, b2, wt2, biases);
  hipLaunchKernelGGL(conv_kernel, dim3(1024), dim3(512), 0, stream, x, wt2,
                     biases, out);
}

// Round 4
// 174.558 us; speedup vs baseline: 1.0993x; 1.0275x over previous
//
#include <hip/hip_runtime.h>

// AdaptiveConv2d v5: prep kernel (hypernet + NCHW->bordered-NHWC-bf16
// transpose) decouples the x transpose from conv. Conv: weights in LDS
// (global_load_lds, conflict-free ds_read_b128 A-frags), B-frags direct
// from global xh (L1/L2-hot, immediate-offset addressing), one barrier.
// Falls back to v4 kernels if workspace is too small.

typedef __bf16 bf16;
typedef __bf16 bf16x8 __attribute__((ext_vector_type(8)));
typedef float f32x4 __attribute__((ext_vector_type(4)));

#define NB 16
#define CI 64
#define CO 64
#define HH 128
#define WW 128
#define TS 16
#define HALO 18           // TS + 2
#define NPL (HALO * HALO) // 324 halo pixels (fallback path)
#define NKW 36864         // CO*CI*9
#define NROWS 36928
#define XHW 130           // bordered NHWC width/height
#define WT2_BYTES ((size_t)NB * 9 * 4096 * 2)       // 1,179,648
#define BIAS_BYTES 4096
#define XH_BYTES ((size_t)NB * XHW * XHW * CI * 2)  // 34,611,200
#define WS_NEED (WT2_BYTES + BIAS_BYTES + XH_BYTES)

typedef const __attribute__((address_space(1))) void* gas_ptr;
typedef __attribute__((address_space(3))) void* las_ptr;

// ---------------- prep: hypernetwork + x transpose ----------------
// blocks 0..144: hyper (each thread owns one W2 row, loops 16 samples;
// kernels land pre-swizzled for the conv A-fragment:
//   elem off = ((b*9+tap)*8 + g*2 + kh)*512 + (q*16+m)*8 + j
//   g=co>>4, m=co&15, kh=ci>>5, q=(ci>>3)&3, j=ci&7 ).
// blocks 145+: one (sample, y') row of xh [16][130][130][64] bf16 with
// zero border; coalesced fp32 row reads, 16B-granule contiguous writes.
__global__ __launch_bounds__(256)
void prep_kernel(const float* __restrict__ x, const float* __restrict__ z,
                 const float* __restrict__ W0, const float* __restrict__ b0,
                 const float* __restrict__ W1, const float* __restrict__ b1,
                 const float* __restrict__ W2, const float* __restrict__ b2,
                 bf16* __restrict__ wt2, float* __restrict__ biases,
                 bf16* __restrict__ xh) {
  const int tid = threadIdx.x;
  if (blockIdx.x < 145) {
    __shared__ float h1s[NB][30];
    if (tid < NB) {
      float h0[20];
      #pragma unroll
      for (int i = 0; i < 20; ++i) {
        float s = b0[i];
        #pragma unroll
        for (int j = 0; j < 16; ++j) s += W0[i * 16 + j] * z[tid * 16 + j];
        h0[i] = fmaxf(s, 0.f);
      }
      #pragma unroll
      for (int i = 0; i < 30; ++i) {
        float s = b1[i];
        #pragma unroll
        for (int j = 0; j < 20; ++j) s += W1[i * 20 + j] * h0[j];
        h1s[tid][i] = fmaxf(s, 0.f);
      }
    }
    __syncthreads();
    const int r = blockIdx.x * 256 + tid;
    if (r >= NROWS) return;
    float w2r[30];
    #pragma unroll
    for (int j = 0; j < 30; ++j) w2r[j] = W2[r * 30 + j];
    const float bb = b2[r];
    const bool isk = r < NKW;
    size_t base = 0;
    if (isk) {
      const int co = r / 576;
      const int rem = r - co * 576;
      const int ci = rem / 9;
      const int tap = rem - ci * 9;
      const int g = co >> 4, mm = co & 15;
      const int kh = ci >> 5, qq = (ci >> 3) & 3, jj = ci & 7;
      base = (size_t)(tap * 8 + g * 2 + kh) * 512 + (size_t)(qq * 16 + mm) * 8 + jj;
    }
    for (int b = 0; b < NB; ++b) {
      float s = bb;
      #pragma unroll
      for (int j = 0; j < 30; ++j) s += w2r[j] * h1s[b][j];
      s = fmaxf(s, 0.f);
      if (isk)
        wt2[(size_t)b * (9 * 4096) + base] = (bf16)s;
      else
        biases[b * CO + (r - NKW)] = s;
    }
    return;
  }

  // ---- transpose blocks ----
  const int bi = blockIdx.x - 145;
  const int b = bi / XHW;
  const int yp = bi - b * XHW; // 0..129
  bf16* row = xh + ((size_t)(b * XHW + yp)) * XHW * CI;
  const bf16x8 zero8 = {};
  if (yp == 0 || yp == XHW - 1) { // full zero row
    for (int g = tid; g < XHW * 8; g += 256)
      *reinterpret_cast<bf16x8*>(row + g * 8) = zero8;
    return;
  }
  // x' border zeros (x'=0 and x'=129, 8 granules each)
  if (tid < 8)
    *reinterpret_cast<bf16x8*>(row + tid * 8) = zero8;
  else if (tid >= 248)
    *reinterpret_cast<bf16x8*>(row + (XHW - 1) * CI + (tid - 248) * 8) = zero8;

  const int px = tid & 127;        // 0..127
  const int c0 = (tid >> 7) * 32;  // 0 or 32
  const float* src =
      x + (((size_t)b * CI + c0) << 14) + ((size_t)(yp - 1) << 7) + px;
  bf16x8 v[4];
  #pragma unroll
  for (int g = 0; g < 4; ++g)
    #pragma unroll
    for (int j = 0; j < 8; ++j)
      v[g][j] = (bf16)src[((size_t)(g * 8 + j)) << 14];
  bf16* dst = row + (px + 1) * CI + c0;
  #pragma unroll
  for (int g = 0; g < 4; ++g)
    *reinterpret_cast<bf16x8*>(dst + g * 8) = v[g];
}

// ---------------- conv v5 (implicit GEMM, bf16 MFMA) ----------------
// 1D grid 1024, XCD-swizzled (XCD k <- 2 complete samples). Block: 512
// thr = 8 waves, 1 sample x 16x16 px x all 64 co; wave wv owns rows
// {2wv,2wv+1}, acc[4 co-groups][2 rows]. Weights (73,728B, all 9 taps)
// staged once via global_load_lds dwordx4 (linear dest == gll semantics);
// A-frags = contiguous ds_read_b128 (conflict-free). B-frags read direct
// from bordered global xh via 4 row pointers + immediate offsets,
// double-buffered across the unrolled tap loop. ONE barrier.
__global__ __launch_bounds__(512, 4)
void conv_kernel(const bf16* __restrict__ xh, const bf16* __restrict__ wt2,
                 const float* __restrict__ bias, float* __restrict__ out) {
  __shared__ __align__(16) bf16 wts[9 * 4096]; // 73,728 B -> 2 blocks/CU

  const int id = (blockIdx.x & 7) * 128 + (blockIdx.x >> 3); // bijective
  const int b = id >> 6;
  const int x0 = (id & 7) * TS;
  const int y0 = ((id >> 3) & 7) * TS;

  const int tid = threadIdx.x;
  const int lane = tid & 63;
  const int wv = tid >> 6; // 0..7
  const int m = lane & 15;
  const int q = lane >> 4;

  // ---- stage all weights global->LDS (9 x 16B per thread) ----
  {
    const bf16* g = wt2 + (size_t)b * (9 * 4096);
    #pragma unroll
    for (int k = 0; k < 9; ++k) {
      const int off = (k * 512 + wv * 64) * 8; // elements; wave-uniform LDS base
      __builtin_amdgcn_global_load_lds((gas_ptr)(g + off + lane * 8),
                                       (las_ptr)(wts + off), 16, 0, 0);
    }
  }

  // ---- B row pointers: y' = y0+ty0 + (j+dy), x' = x0+m (+dx) ----
  const int ty0 = wv * 2;
  const bf16* xb = xh + (((size_t)b * XHW + (y0 + ty0)) * XHW + (x0 + m)) * CI +
                   q * 8;
  const bf16* rp[4];
  #pragma unroll
  for (int r = 0; r < 4; ++r) rp[r] = xb + (size_t)r * XHW * CI;

  f32x4 acc[4][2];
  #pragma unroll
  for (int i = 0; i < 4; ++i) {
    acc[i][0] = (f32x4){0.f, 0.f, 0.f, 0.f};
    acc[i][1] = (f32x4){0.f, 0.f, 0.f, 0.f};
  }

  bf16x8 bb[2][2][2]; // [buf][kh][j]
  // prefetch tap 0 B-frags (dy=0, dx=0)
  #pragma unroll
  for (int kh = 0; kh < 2; ++kh)
    #pragma unroll
    for (int j = 0; j < 2; ++j)
      bb[0][kh][j] = *reinterpret_cast<const bf16x8*>(rp[j] + kh * 32);

  __syncthreads(); // weights staged (implicit vmcnt(0) drain)

  #pragma unroll
  for (int tap = 0; tap < 9; ++tap) {
    const int cur = tap & 1, nxt = cur ^ 1; // compile-time after unroll
    if (tap < 8) { // prefetch next tap's B-frags; overlaps this tap's MFMAs
      const int dyn = (tap + 1) / 3, dxn = (tap + 1) - dyn * 3;
      #pragma unroll
      for (int kh = 0; kh < 2; ++kh)
        #pragma unroll
        for (int j = 0; j < 2; ++j)
          bb[nxt][kh][j] = *reinterpret_cast<const bf16x8*>(
              rp[j + dyn] + dxn * 64 + kh * 32);
    }
    // A-frags from LDS (contiguous 1KB per frag -> conflict-free b128)
    bf16x8 a[4][2];
    #pragma unroll
    for (int i = 0; i < 4; ++i)
      #pragma unroll
      for (int kh = 0; kh < 2; ++kh)
        a[i][kh] = *reinterpret_cast<const bf16x8*>(
            wts + tap * 4096 + (i * 2 + kh) * 512 + lane * 8);
    __builtin_amdgcn_s_setprio(1);
    #pragma unroll
    for (int kh = 0; kh < 2; ++kh)
      #pragma unroll
      for (int j = 0; j < 2; ++j)
        #pragma unroll
        for (int i = 0; i < 4; ++i)
          acc[i][j] = __builtin_amdgcn_mfma_f32_16x16x32_bf16(
              a[i][kh], bb[cur][kh][j], acc[i][j], 0, 0, 0);
    __builtin_amdgcn_s_setprio(0);
  }

  // epilogue: D col = m (px), row = q*4+r (co in group); co = i*16 + q*4 + r
  const float* bp = bias + b * CO;
  float* ob = out + ((size_t)(b * CO) << 14) + (size_t)((y0 + ty0) * WW + x0 + m);
  #pragma unroll
  for (int i = 0; i < 4; ++i)
    #pragma unroll
    for (int j = 0; j < 2; ++j)
      #pragma unroll
      for (int r = 0; r < 4; ++r) {
        const int co = i * 16 + q * 4 + r;
        float v = acc[i][j][r] + bp[co];
        ob[((size_t)co << 14) + j * WW] = fmaxf(v, 0.f);
      }
}

// ---------------- fallback conv (v4, reads raw x) ----------------
__global__ __launch_bounds__(512, 4)
void conv_fb(const float* __restrict__ x, const bf16* __restrict__ wt2,
             const float* __restrict__ bias, float* __restrict__ out) {
  __shared__ __align__(16) bf16 xt[NPL * 64];

  const int id = (blockIdx.x & 7) * 128 + (blockIdx.x >> 3);
  const int b = id >> 6;
  const int x0 = (id & 7) * TS;
  const int y0 = ((id >> 3) & 7) * TS;

  const int tid = threadIdx.x;
  const int lane = tid & 63;
  const int wv = tid >> 6;
  const int m = lane & 15;
  const int q = lane >> 4;

  const char* wbase = (const char*)wt2 + (size_t)b * (9 * 8192) + lane * 16;

  bf16x8 abuf[2][4][2];
  #pragma unroll
  for (int i = 0; i < 4; ++i)
    #pragma unroll
    for (int kh = 0; kh < 2; ++kh)
      abuf[0][i][kh] =
          *reinterpret_cast<const bf16x8*>(wbase + (i * 2 + kh) * 1024);

  const float* xb = x + ((size_t)b << 20);
  for (int t = 0; t < 6; ++t) {
    const int it = min(tid + t * 512, NPL * 8 - 1);
    const int cig = ((it >> 2) * 810) >> 16;
    const int pl = it - cig * 324;
    const int py = (pl * 57) >> 10;
    const int px = pl - py * 18;
    int gy = y0 + py - 1, gx = x0 + px - 1;
    const bool inb = ((unsigned)gy < (unsigned)HH) & ((unsigned)gx < (unsigned)WW);
    gy = min(max(gy, 0), HH - 1);
    gx = min(max(gx, 0), WW - 1);
    const float* src = xb + ((size_t)cig << 17) + (gy << 7) + gx;
    bf16x8 v8;
    #pragma unroll
    for (int j = 0; j < 8; ++j)
      v8[j] = inb ? (bf16)src[(size_t)j << 14] : (bf16)0.f;
    if (!(t == 5 && tid >= NPL * 8 - 5 * 512))
      *reinterpret_cast<bf16x8*>(reinterpret_cast<char*>(xt) + (pl << 7) +
                                 ((cig ^ (pl & 7)) << 4)) = v8;
  }

  f32x4 acc[4][2];
  #pragma unroll
  for (int i = 0; i < 4; ++i) {
    acc[i][0] = (f32x4){0.f, 0.f, 0.f, 0.f};
    acc[i][1] = (f32x4){0.f, 0.f, 0.f, 0.f};
  }
  const int ty0 = wv * 2;
  __syncthreads();

  #pragma unroll
  for (int tap = 0; tap < 9; ++tap) {
    const int cur = tap & 1, nxt = cur ^ 1;
    if (tap < 8) {
      const char* wt_n = wbase + (tap + 1) * 8192;
      #pragma unroll
      for (int i = 0; i < 4; ++i)
        #pragma unroll
        for (int kh = 0; kh < 2; ++kh)
          abuf[nxt][i][kh] =
              *reinterpret_cast<const bf16x8*>(wt_n + (i * 2 + kh) * 1024);
    }
    const int dy = (tap * 11) >> 5;
    const int dx = tap - dy * 3;
    const int plb = (ty0 + dy) * 18 + dx + m;
    __builtin_amdgcn_s_setprio(1);
    #pragma unroll
    for (int kh = 0; kh < 2; ++kh) {
      const int qk = q + kh * 4;
      #pragma unroll
      for (int j = 0; j < 2; ++j) {
        const int pl = plb + j * 18;
        const bf16x8 bv = *reinterpret_cast<const bf16x8*>(
            reinterpret_cast<const char*>(xt) + (pl << 7) +
            ((qk ^ (pl & 7)) << 4));
        #pragma unroll
        for (int i = 0; i < 4; ++i)
          acc[i][j] = __builtin_amdgcn_mfma_f32_16x16x32_bf16(
              abuf[cur][i][kh], bv, acc[i][j], 0, 0, 0);
      }
    }
    __builtin_amdgcn_s_setprio(0);
  }

  const float* bp = bias + b * CO;
  float* ob = out + ((size_t)(b * CO) << 14) + (size_t)((y0 + ty0) * WW + x0 + m);
  #pragma unroll
  for (int i = 0; i < 4; ++i)
    #pragma unroll
    for (int j = 0; j < 2; ++j)
      #pragma unroll
      for (int r = 0; r < 4; ++r) {
        const int co = i * 16 + q * 4 + r;
        float v = acc[i][j][r] + bp[co];
        ob[((size_t)co << 14) + j * WW] = fmaxf(v, 0.f);
      }
}

extern "C" void kernel_launch(void* const* d_in, const int* in_sizes, int n_in,
                              void* d_out, int out_size, void* d_ws,
                              size_t ws_size, hipStream_t stream) {
  const float* x = (const float*)d_in[0];
  const float* z = (const float*)d_in[1];
  const float* W0 = (const float*)d_in[2];
  const float* b0 = (const float*)d_in[3];
  const float* W1 = (const float*)d_in[4];
  const float* b1 = (const float*)d_in[5];
  const float* W2 = (const float*)d_in[6];
  const float* b2 = (const float*)d_in[7];
  float* out = (float*)d_out;

  bf16* wt2 = (bf16*)d_ws;
  float* biases = (float*)((char*)d_ws + WT2_BYTES);
  bf16* xh = (bf16*)((char*)d_ws + WT2_BYTES + BIAS_BYTES);

  if (ws_size >= WS_NEED) {
    hipLaunchKernelGGL(prep_kernel, dim3(145 + NB * XHW), dim3(256), 0, stream,
                       x, z, W0, b0, W1, b1, W2, b2, wt2, biases, xh);
    hipLaunchKernelGGL(conv_kernel, dim3(1024), dim3(512), 0, stream, xh, wt2,
                       biases, out);
  } else { // workspace too small: v4 path
    hipLaunchKernelGGL(prep_kernel, dim3(145), dim3(256), 0, stream, x, z, W0,
                       b0, W1, b1, W2, b2, wt2, biases, xh);
    hipLaunchKernelGGL(conv_fb, dim3(1024), dim3(512), 0, stream, x, wt2,
                       biases, out);
  }
}

// Round 5
// 164.597 us; speedup vs baseline: 1.1658x; 1.0605x over previous
//
#include <hip/hip_runtime.h>

// AdaptiveConv2d v6: prep (hypernet + NCHW->bordered-NHWC-bf16 transpose)
// unchanged from v5. Conv = v4's LDS-B tap loop + v5's xh: x tile staged
// via global_load_lds with pre-swizzled per-lane SOURCE (linear LDS dest,
// swizzled read => conflict-free b128 both sides), weights double-buffered
// in registers (XCD-local L2 hits). One barrier. Falls back if ws small.

typedef __bf16 bf16;
typedef __bf16 bf16x8 __attribute__((ext_vector_type(8)));
typedef float f32x4 __attribute__((ext_vector_type(4)));

#define NB 16
#define CI 64
#define CO 64
#define HH 128
#define WW 128
#define TS 16
#define HALO 18           // TS + 2
#define NPL (HALO * HALO) // 324 halo pixels
#define NKW 36864         // CO*CI*9
#define NROWS 36928
#define XHW 130           // bordered NHWC width/height
#define WT2_BYTES ((size_t)NB * 9 * 4096 * 2)       // 1,179,648
#define BIAS_BYTES 4096
#define XH_BYTES ((size_t)NB * XHW * XHW * CI * 2)  // 34,611,200
#define WS_NEED (WT2_BYTES + BIAS_BYTES + XH_BYTES)

typedef const __attribute__((address_space(1))) void* gas_ptr;
typedef __attribute__((address_space(3))) void* las_ptr;

// ---------------- prep: hypernetwork + x transpose ----------------
// blocks 0..144: hyper (thread owns one W2 row, loops 16 samples; kernel
// rows land pre-swizzled for the conv A-fragment:
//   elem off = ((b*9+tap)*8 + g*2 + kh)*512 + (q*16+m)*8 + j ).
// blocks 145+: one (sample, y') row of xh [16][130][130][64] bf16 with
// zero border; coalesced fp32 row reads, 16B-granule contiguous writes.
__global__ __launch_bounds__(256)
void prep_kernel(const float* __restrict__ x, const float* __restrict__ z,
                 const float* __restrict__ W0, const float* __restrict__ b0,
                 const float* __restrict__ W1, const float* __restrict__ b1,
                 const float* __restrict__ W2, const float* __restrict__ b2,
                 bf16* __restrict__ wt2, float* __restrict__ biases,
                 bf16* __restrict__ xh) {
  const int tid = threadIdx.x;
  if (blockIdx.x < 145) {
    __shared__ float h1s[NB][30];
    if (tid < NB) {
      float h0[20];
      #pragma unroll
      for (int i = 0; i < 20; ++i) {
        float s = b0[i];
        #pragma unroll
        for (int j = 0; j < 16; ++j) s += W0[i * 16 + j] * z[tid * 16 + j];
        h0[i] = fmaxf(s, 0.f);
      }
      #pragma unroll
      for (int i = 0; i < 30; ++i) {
        float s = b1[i];
        #pragma unroll
        for (int j = 0; j < 20; ++j) s += W1[i * 20 + j] * h0[j];
        h1s[tid][i] = fmaxf(s, 0.f);
      }
    }
    __syncthreads();
    const int r = blockIdx.x * 256 + tid;
    if (r >= NROWS) return;
    float w2r[30];
    #pragma unroll
    for (int j = 0; j < 30; ++j) w2r[j] = W2[r * 30 + j];
    const float bb = b2[r];
    const bool isk = r < NKW;
    size_t base = 0;
    if (isk) {
      const int co = r / 576;
      const int rem = r - co * 576;
      const int ci = rem / 9;
      const int tap = rem - ci * 9;
      const int g = co >> 4, mm = co & 15;
      const int kh = ci >> 5, qq = (ci >> 3) & 3, jj = ci & 7;
      base = (size_t)(tap * 8 + g * 2 + kh) * 512 + (size_t)(qq * 16 + mm) * 8 + jj;
    }
    for (int b = 0; b < NB; ++b) {
      float s = bb;
      #pragma unroll
      for (int j = 0; j < 30; ++j) s += w2r[j] * h1s[b][j];
      s = fmaxf(s, 0.f);
      if (isk)
        wt2[(size_t)b * (9 * 4096) + base] = (bf16)s;
      else
        biases[b * CO + (r - NKW)] = s;
    }
    return;
  }

  // ---- transpose blocks ----
  const int bi = blockIdx.x - 145;
  const int b = bi / XHW;
  const int yp = bi - b * XHW; // 0..129
  bf16* row = xh + ((size_t)(b * XHW + yp)) * XHW * CI;
  const bf16x8 zero8 = {};
  if (yp == 0 || yp == XHW - 1) { // full zero row
    for (int g = tid; g < XHW * 8; g += 256)
      *reinterpret_cast<bf16x8*>(row + g * 8) = zero8;
    return;
  }
  // x' border zeros (x'=0 and x'=129, 8 granules each)
  if (tid < 8)
    *reinterpret_cast<bf16x8*>(row + tid * 8) = zero8;
  else if (tid >= 248)
    *reinterpret_cast<bf16x8*>(row + (XHW - 1) * CI + (tid - 248) * 8) = zero8;

  const int px = tid & 127;        // 0..127
  const int c0 = (tid >> 7) * 32;  // 0 or 32
  const float* src =
      x + (((size_t)b * CI + c0) << 14) + ((size_t)(yp - 1) << 7) + px;
  bf16x8 v[4];
  #pragma unroll
  for (int g = 0; g < 4; ++g)
    #pragma unroll
    for (int j = 0; j < 8; ++j)
      v[g][j] = (bf16)src[((size_t)(g * 8 + j)) << 14];
  bf16* dst = row + (px + 1) * CI + c0;
  #pragma unroll
  for (int g = 0; g < 4; ++g)
    *reinterpret_cast<bf16x8*>(dst + g * 8) = v[g];
}

// ---------------- conv v6 (implicit GEMM, bf16 MFMA) ----------------
// 1D grid 1024, XCD-swizzled (XCD k <- 2 complete samples). Block: 512
// thr = 8 waves, 1 sample x 16x16 px x all 64 co; wave wv rows {2wv,2wv+1},
// acc[4 co-groups][2 rows]. x tile: global_load_lds from xh, LDS granule
// e=(pl,g) sourced from xh granule (pl, g^(pl&7)) -> linear dest, reads use
// v4's verified swizzled formula (conflict-free both sides). Weights:
// double-buffered registers from L2 (XCD-local). ONE barrier.
__global__ __launch_bounds__(512, 4)
void conv_kernel(const bf16* __restrict__ xh, const bf16* __restrict__ wt2,
                 const float* __restrict__ bias, float* __restrict__ out) {
  __shared__ __align__(16) bf16 xt[2624 * 8]; // 41,984 B (2592 + tail pad)

  const int id = (blockIdx.x & 7) * 128 + (blockIdx.x >> 3); // bijective
  const int b = id >> 6;
  const int x0 = (id & 7) * TS;
  const int y0 = ((id >> 3) & 7) * TS;

  const int tid = threadIdx.x;
  const int lane = tid & 63;
  const int wv = tid >> 6; // 0..7
  const int m = lane & 15;
  const int q = lane >> 4;

  const char* wbase = (const char*)wt2 + (size_t)b * 73728 + lane * 16;

  // ---- prefetch tap-0 A-fragments (first into the vmem queue) ----
  bf16x8 abuf[2][4][2];
  #pragma unroll
  for (int i = 0; i < 4; ++i)
    #pragma unroll
    for (int kh = 0; kh < 2; ++kh)
      abuf[0][i][kh] =
          *reinterpret_cast<const bf16x8*>(wbase + (i * 2 + kh) * 1024);

  // ---- stage x tile: 2592 granules of 16B via global_load_lds ----
  // LDS granule e holds xh granule (pl, g^(pl&7)); dest strictly linear.
  {
    const char* xb =
        (const char*)xh + (((size_t)(b * XHW + y0)) * XHW + x0) * 128;
    #pragma unroll
    for (int k = 0; k < 5; ++k) {
      const int e = k * 512 + tid;
      const int pl = e >> 3;
      const int gs = (e & 7) ^ (pl & 7);
      const int py = (pl * 57) >> 10; // pl/18, exact for pl < 512
      const int px = pl - py * 18;
      __builtin_amdgcn_global_load_lds(
          (gas_ptr)(xb + ((py * XHW + px) << 7) + (gs << 4)),
          (las_ptr)((char*)xt + ((k * 512 + wv * 64) << 4)), 16, 0, 0);
    }
    if (wv == 0) { // tail: granules 2560..2591 (+32 clamped dups into pad)
      const int esrc = min(2560 + lane, 2591);
      const int pl = esrc >> 3;
      const int gs = (esrc & 7) ^ (pl & 7);
      const int py = (pl * 57) >> 10;
      const int px = pl - py * 18;
      __builtin_amdgcn_global_load_lds(
          (gas_ptr)(xb + ((py * XHW + px) << 7) + (gs << 4)),
          (las_ptr)((char*)xt + (2560 << 4)), 16, 0, 0);
    }
  }

  f32x4 acc[4][2];
  #pragma unroll
  for (int i = 0; i < 4; ++i) {
    acc[i][0] = (f32x4){0.f, 0.f, 0.f, 0.f};
    acc[i][1] = (f32x4){0.f, 0.f, 0.f, 0.f};
  }

  const int ty0 = wv * 2;

  __syncthreads(); // staging drained (vmcnt(0) implicit before barrier)

  #pragma unroll
  for (int tap = 0; tap < 9; ++tap) {
    const int cur = tap & 1, nxt = cur ^ 1; // compile-time after unroll
    if (tap < 8) { // prefetch next tap's A-frags; overlaps this tap's MFMAs
      const char* wt_n = wbase + (tap + 1) * 8192;
      #pragma unroll
      for (int i = 0; i < 4; ++i)
        #pragma unroll
        for (int kh = 0; kh < 2; ++kh)
          abuf[nxt][i][kh] =
              *reinterpret_cast<const bf16x8*>(wt_n + (i * 2 + kh) * 1024);
    }
    const int dy = (tap * 11) >> 5; // tap/3
    const int dx = tap - dy * 3;
    const int plb = (ty0 + dy) * 18 + dx + m;
    __builtin_amdgcn_s_setprio(1);
    #pragma unroll
    for (int kh = 0; kh < 2; ++kh) {
      const int qk = q + kh * 4;
      #pragma unroll
      for (int j = 0; j < 2; ++j) {
        const int pl = plb + j * 18;
        const bf16x8 bv = *reinterpret_cast<const bf16x8*>(
            reinterpret_cast<const char*>(xt) + (pl << 7) +
            ((qk ^ (pl & 7)) << 4));
        #pragma unroll
        for (int i = 0; i < 4; ++i)
          acc[i][j] = __builtin_amdgcn_mfma_f32_16x16x32_bf16(
              abuf[cur][i][kh], bv, acc[i][j], 0, 0, 0);
      }
    }
    __builtin_amdgcn_s_setprio(0);
  }

  // epilogue: D col = m (px), row = q*4+r (co in group); co = i*16 + q*4 + r
  const float* bp = bias + b * CO;
  float* ob = out + ((size_t)(b * CO) << 14) + (size_t)((y0 + ty0) * WW + x0 + m);
  #pragma unroll
  for (int i = 0; i < 4; ++i)
    #pragma unroll
    for (int j = 0; j < 2; ++j)
      #pragma unroll
      for (int r = 0; r < 4; ++r) {
        const int co = i * 16 + q * 4 + r;
        float v = acc[i][j][r] + bp[co];
        ob[((size_t)co << 14) + j * WW] = fmaxf(v, 0.f);
      }
}

// ---------------- fallback conv (v4, reads raw x) ----------------
__global__ __launch_bounds__(512, 4)
void conv_fb(const float* __restrict__ x, const bf16* __restrict__ wt2,
             const float* __restrict__ bias, float* __restrict__ out) {
  __shared__ __align__(16) bf16 xt[NPL * 64];

  const int id = (blockIdx.x & 7) * 128 + (blockIdx.x >> 3);
  const int b = id >> 6;
  const int x0 = (id & 7) * TS;
  const int y0 = ((id >> 3) & 7) * TS;

  const int tid = threadIdx.x;
  const int lane = tid & 63;
  const int wv = tid >> 6;
  const int m = lane & 15;
  const int q = lane >> 4;

  const char* wbase = (const char*)wt2 + (size_t)b * 73728 + lane * 16;

  bf16x8 abuf[2][4][2];
  #pragma unroll
  for (int i = 0; i < 4; ++i)
    #pragma unroll
    for (int kh = 0; kh < 2; ++kh)
      abuf[0][i][kh] =
          *reinterpret_cast<const bf16x8*>(wbase + (i * 2 + kh) * 1024);

  const float* xb = x + ((size_t)b << 20);
  for (int t = 0; t < 6; ++t) {
    const int it = min(tid + t * 512, NPL * 8 - 1);
    const int cig = ((it >> 2) * 810) >> 16;
    const int pl = it - cig * 324;
    const int py = (pl * 57) >> 10;
    const int px = pl - py * 18;
    int gy = y0 + py - 1, gx = x0 + px - 1;
    const bool inb = ((unsigned)gy < (unsigned)HH) & ((unsigned)gx < (unsigned)WW);
    gy = min(max(gy, 0), HH - 1);
    gx = min(max(gx, 0), WW - 1);
    const float* src = xb + ((size_t)cig << 17) + (gy << 7) + gx;
    bf16x8 v8;
    #pragma unroll
    for (int j = 0; j < 8; ++j)
      v8[j] = inb ? (bf16)src[(size_t)j << 14] : (bf16)0.f;
    if (!(t == 5 && tid >= NPL * 8 - 5 * 512))
      *reinterpret_cast<bf16x8*>(reinterpret_cast<char*>(xt) + (pl << 7) +
                                 ((cig ^ (pl & 7)) << 4)) = v8;
  }

  f32x4 acc[4][2];
  #pragma unroll
  for (int i = 0; i < 4; ++i) {
    acc[i][0] = (f32x4){0.f, 0.f, 0.f, 0.f};
    acc[i][1] = (f32x4){0.f, 0.f, 0.f, 0.f};
  }
  const int ty0 = wv * 2;
  __syncthreads();

  #pragma unroll
  for (int tap = 0; tap < 9; ++tap) {
    const int cur = tap & 1, nxt = cur ^ 1;
    if (tap < 8) {
      const char* wt_n = wbase + (tap + 1) * 8192;
      #pragma unroll
      for (int i = 0; i < 4; ++i)
        #pragma unroll
        for (int kh = 0; kh < 2; ++kh)
          abuf[nxt][i][kh] =
              *reinterpret_cast<const bf16x8*>(wt_n + (i * 2 + kh) * 1024);
    }
    const int dy = (tap * 11) >> 5;
    const int dx = tap - dy * 3;
    const int plb = (ty0 + dy) * 18 + dx + m;
    __builtin_amdgcn_s_setprio(1);
    #pragma unroll
    for (int kh = 0; kh < 2; ++kh) {
      const int qk = q + kh * 4;
      #pragma unroll
      for (int j = 0; j < 2; ++j) {
        const int pl = plb + j * 18;
        const bf16x8 bv = *reinterpret_cast<const bf16x8*>(
            reinterpret_cast<const char*>(xt) + (pl << 7) +
            ((qk ^ (pl & 7)) << 4));
        #pragma unroll
        for (int i = 0; i < 4; ++i)
          acc[i][j] = __builtin_amdgcn_mfma_f32_16x16x32_bf16(
              abuf[cur][i][kh], bv, acc[i][j], 0, 0, 0);
      }
    }
    __builtin_amdgcn_s_setprio(0);
  }

  const float* bp = bias + b * CO;
  float* ob = out + ((size_t)(b * CO) << 14) + (size_t)((y0 + ty0) * WW + x0 + m);
  #pragma unroll
  for (int i = 0; i < 4; ++i)
    #pragma unroll
    for (int j = 0; j < 2; ++j)
      #pragma unroll
      for (int r = 0; r < 4; ++r) {
        const int co = i * 16 + q * 4 + r;
        float v = acc[i][j][r] + bp[co];
        ob[((size_t)co << 14) + j * WW] = fmaxf(v, 0.f);
      }
}

extern "C" void kernel_launch(void* const* d_in, const int* in_sizes, int n_in,
                              void* d_out, int out_size, void* d_ws,
                              size_t ws_size, hipStream_t stream) {
  const float* x = (const float*)d_in[0];
  const float* z = (const float*)d_in[1];
  const float* W0 = (const float*)d_in[2];
  const float* b0 = (const float*)d_in[3];
  const float* W1 = (const float*)d_in[4];
  const float* b1 = (const float*)d_in[5];
  const float* W2 = (const float*)d_in[6];
  const float* b2 = (const float*)d_in[7];
  float* out = (float*)d_out;

  bf16* wt2 = (bf16*)d_ws;
  float* biases = (float*)((char*)d_ws + WT2_BYTES);
  bf16* xh = (bf16*)((char*)d_ws + WT2_BYTES + BIAS_BYTES);

  if (ws_size >= WS_NEED) {
    hipLaunchKernelGGL(prep_kernel, dim3(145 + NB * XHW), dim3(256), 0, stream,
                       x, z, W0, b0, W1, b1, W2, b2, wt2, biases, xh);
    hipLaunchKernelGGL(conv_kernel, dim3(1024), dim3(512), 0, stream, xh, wt2,
                       biases, out);
  } else { // workspace too small: v4 path
    hipLaunchKernelGGL(prep_kernel, dim3(145), dim3(256), 0, stream, x, z, W0,
                       b0, W1, b1, W2, b2, wt2, biases, xh);
    hipLaunchKernelGGL(conv_fb, dim3(1024), dim3(512), 0, stream, x, wt2,
                       biases, out);
  }
}

// Round 6
// 163.376 us; speedup vs baseline: 1.1745x; 1.0075x over previous
//
#include <hip/hip_runtime.h>

// AdaptiveConv2d v7: v6 conv unchanged. Prep transpose now bounces through
// LDS: coalesced fp32 reads -> XOR-swizzled LDS granules (v4-verified
// conflict-free pattern) -> linear-granule global writes (4KB contiguous
// per wave) with border zeros folded in. Fixes the lane-scattered 128B-
// stride xh writes that held prep at 1.8 TB/s.

typedef __bf16 bf16;
typedef __bf16 bf16x8 __attribute__((ext_vector_type(8)));
typedef float f32x4 __attribute__((ext_vector_type(4)));

#define NB 16
#define CI 64
#define CO 64
#define HH 128
#define WW 128
#define TS 16
#define HALO 18           // TS + 2
#define NPL (HALO * HALO) // 324 halo pixels
#define NKW 36864         // CO*CI*9
#define NROWS 36928
#define XHW 130           // bordered NHWC width/height
#define WT2_BYTES ((size_t)NB * 9 * 4096 * 2)       // 1,179,648
#define BIAS_BYTES 4096
#define XH_BYTES ((size_t)NB * XHW * XHW * CI * 2)  // 34,611,200
#define WS_NEED (WT2_BYTES + BIAS_BYTES + XH_BYTES)

typedef const __attribute__((address_space(1))) void* gas_ptr;
typedef __attribute__((address_space(3))) void* las_ptr;

// ---------------- prep: hypernetwork + x transpose ----------------
// blocks 0..144: hyper (thread owns one W2 row, loops 16 samples; kernel
// rows land pre-swizzled for the conv A-fragment:
//   elem off = ((b*9+tap)*8 + g*2 + kh)*512 + (q*16+m)*8 + j ).
// blocks 145+: one (sample, y') row of xh [16][130][130][64] bf16 with
// zero border. Read coalesced fp32 -> regs -> swizzled LDS granules ->
// linear-granule coalesced global writes.
__global__ __launch_bounds__(256)
void prep_kernel(const float* __restrict__ x, const float* __restrict__ z,
                 const float* __restrict__ W0, const float* __restrict__ b0,
                 const float* __restrict__ W1, const float* __restrict__ b1,
                 const float* __restrict__ W2, const float* __restrict__ b2,
                 bf16* __restrict__ wt2, float* __restrict__ biases,
                 bf16* __restrict__ xh) {
  const int tid = threadIdx.x;
  if (blockIdx.x < 145) {
    __shared__ float h1s[NB][30];
    if (tid < NB) {
      float h0[20];
      #pragma unroll
      for (int i = 0; i < 20; ++i) {
        float s = b0[i];
        #pragma unroll
        for (int j = 0; j < 16; ++j) s += W0[i * 16 + j] * z[tid * 16 + j];
        h0[i] = fmaxf(s, 0.f);
      }
      #pragma unroll
      for (int i = 0; i < 30; ++i) {
        float s = b1[i];
        #pragma unroll
        for (int j = 0; j < 20; ++j) s += W1[i * 20 + j] * h0[j];
        h1s[tid][i] = fmaxf(s, 0.f);
      }
    }
    __syncthreads();
    const int r = blockIdx.x * 256 + tid;
    if (r >= NROWS) return;
    float w2r[30];
    #pragma unroll
    for (int j = 0; j < 30; ++j) w2r[j] = W2[r * 30 + j];
    const float bb = b2[r];
    const bool isk = r < NKW;
    size_t base = 0;
    if (isk) {
      const int co = r / 576;
      const int rem = r - co * 576;
      const int ci = rem / 9;
      const int tap = rem - ci * 9;
      const int g = co >> 4, mm = co & 15;
      const int kh = ci >> 5, qq = (ci >> 3) & 3, jj = ci & 7;
      base = (size_t)(tap * 8 + g * 2 + kh) * 512 + (size_t)(qq * 16 + mm) * 8 + jj;
    }
    for (int b = 0; b < NB; ++b) {
      float s = bb;
      #pragma unroll
      for (int j = 0; j < 30; ++j) s += w2r[j] * h1s[b][j];
      s = fmaxf(s, 0.f);
      if (isk)
        wt2[(size_t)b * (9 * 4096) + base] = (bf16)s;
      else
        biases[b * CO + (r - NKW)] = s;
    }
    return;
  }

  // ---- transpose blocks: one (b, y') row ----
  const int bi = blockIdx.x - 145;
  const int b = bi / XHW;
  const int yp = bi - b * XHW; // 0..129
  bf16* row = xh + ((size_t)(b * XHW + yp)) * XHW * CI;
  const bf16x8 zero8 = {};
  if (yp == 0 || yp == XHW - 1) { // full zero row, coalesced
    for (int g = tid; g < XHW * 8; g += 256)
      *reinterpret_cast<bf16x8*>(row + g * 8) = zero8;
    return;
  }

  __shared__ __align__(16) bf16 xls[128 * 64]; // 16 KB staging row

  // phase 1: coalesced fp32 reads (all 32 issued up-front), convert,
  // XOR-swizzled LDS granule writes (v4-verified conflict-free pattern)
  {
    const int px = tid & 127;        // 0..127
    const int c0g = (tid >> 7) * 4;  // granule base: 0 or 4
    const float* src =
        x + (((size_t)b * CI + c0g * 8) << 14) + ((size_t)(yp - 1) << 7) + px;
    float vv[32];
    #pragma unroll
    for (int u = 0; u < 32; ++u) vv[u] = src[((size_t)u) << 14];
    #pragma unroll
    for (int g = 0; g < 4; ++g) {
      bf16x8 v;
      #pragma unroll
      for (int j = 0; j < 8; ++j) v[j] = (bf16)vv[g * 8 + j];
      const int gr = c0g + g;
      *reinterpret_cast<bf16x8*>(reinterpret_cast<char*>(xls) + (px << 7) +
                                 ((gr ^ (px & 7)) << 4)) = v;
    }
  }
  __syncthreads();

  // phase 2: linear granule order -> fully coalesced global writes;
  // border granules (px'=0,129) emit zeros.
  #pragma unroll
  for (int k = 0; k < 5; ++k) {
    const int it = k * 256 + tid;
    if (it >= XHW * 8) break; // k=4: only tid<16
    const int pxp = it >> 3, gr = it & 7;
    bf16x8 v = zero8;
    if (pxp >= 1 && pxp <= 128) {
      const int px = pxp - 1;
      v = *reinterpret_cast<const bf16x8*>(
          reinterpret_cast<const char*>(xls) + (px << 7) +
          ((gr ^ (px & 7)) << 4));
    }
    *reinterpret_cast<bf16x8*>(row + it * 8) = v;
  }
}

// ---------------- conv v6 (implicit GEMM, bf16 MFMA) — unchanged ----------------
// 1D grid 1024, XCD-swizzled (XCD k <- 2 complete samples). Block: 512
// thr = 8 waves, 1 sample x 16x16 px x all 64 co; wave wv rows {2wv,2wv+1},
// acc[4 co-groups][2 rows]. x tile: global_load_lds from xh, LDS granule
// e=(pl,g) sourced from xh granule (pl, g^(pl&7)) -> linear dest, swizzled
// conflict-free reads. Weights: double-buffered registers. ONE barrier.
__global__ __launch_bounds__(512, 4)
void conv_kernel(const bf16* __restrict__ xh, const bf16* __restrict__ wt2,
                 const float* __restrict__ bias, float* __restrict__ out) {
  __shared__ __align__(16) bf16 xt[2624 * 8]; // 41,984 B (2592 + tail pad)

  const int id = (blockIdx.x & 7) * 128 + (blockIdx.x >> 3); // bijective
  const int b = id >> 6;
  const int x0 = (id & 7) * TS;
  const int y0 = ((id >> 3) & 7) * TS;

  const int tid = threadIdx.x;
  const int lane = tid & 63;
  const int wv = tid >> 6; // 0..7
  const int m = lane & 15;
  const int q = lane >> 4;

  const char* wbase = (const char*)wt2 + (size_t)b * 73728 + lane * 16;

  // ---- prefetch tap-0 A-fragments (first into the vmem queue) ----
  bf16x8 abuf[2][4][2];
  #pragma unroll
  for (int i = 0; i < 4; ++i)
    #pragma unroll
    for (int kh = 0; kh < 2; ++kh)
      abuf[0][i][kh] =
          *reinterpret_cast<const bf16x8*>(wbase + (i * 2 + kh) * 1024);

  // ---- stage x tile: 2592 granules of 16B via global_load_lds ----
  {
    const char* xb =
        (const char*)xh + (((size_t)(b * XHW + y0)) * XHW + x0) * 128;
    #pragma unroll
    for (int k = 0; k < 5; ++k) {
      const int e = k * 512 + tid;
      const int pl = e >> 3;
      const int gs = (e & 7) ^ (pl & 7);
      const int py = (pl * 57) >> 10; // pl/18, exact for pl < 512
      const int px = pl - py * 18;
      __builtin_amdgcn_global_load_lds(
          (gas_ptr)(xb + ((py * XHW + px) << 7) + (gs << 4)),
          (las_ptr)((char*)xt + ((k * 512 + wv * 64) << 4)), 16, 0, 0);
    }
    if (wv == 0) { // tail: granules 2560..2591 (+32 clamped dups into pad)
      const int esrc = min(2560 + lane, 2591);
      const int pl = esrc >> 3;
      const int gs = (esrc & 7) ^ (pl & 7);
      const int py = (pl * 57) >> 10;
      const int px = pl - py * 18;
      __builtin_amdgcn_global_load_lds(
          (gas_ptr)(xb + ((py * XHW + px) << 7) + (gs << 4)),
          (las_ptr)((char*)xt + (2560 << 4)), 16, 0, 0);
    }
  }

  f32x4 acc[4][2];
  #pragma unroll
  for (int i = 0; i < 4; ++i) {
    acc[i][0] = (f32x4){0.f, 0.f, 0.f, 0.f};
    acc[i][1] = (f32x4){0.f, 0.f, 0.f, 0.f};
  }

  const int ty0 = wv * 2;

  __syncthreads(); // staging drained (vmcnt(0) implicit before barrier)

  #pragma unroll
  for (int tap = 0; tap < 9; ++tap) {
    const int cur = tap & 1, nxt = cur ^ 1; // compile-time after unroll
    if (tap < 8) { // prefetch next tap's A-frags; overlaps this tap's MFMAs
      const char* wt_n = wbase + (tap + 1) * 8192;
      #pragma unroll
      for (int i = 0; i < 4; ++i)
        #pragma unroll
        for (int kh = 0; kh < 2; ++kh)
          abuf[nxt][i][kh] =
              *reinterpret_cast<const bf16x8*>(wt_n + (i * 2 + kh) * 1024);
    }
    const int dy = (tap * 11) >> 5; // tap/3
    const int dx = tap - dy * 3;
    const int plb = (ty0 + dy) * 18 + dx + m;
    __builtin_amdgcn_s_setprio(1);
    #pragma unroll
    for (int kh = 0; kh < 2; ++kh) {
      const int qk = q + kh * 4;
      #pragma unroll
      for (int j = 0; j < 2; ++j) {
        const int pl = plb + j * 18;
        const bf16x8 bv = *reinterpret_cast<const bf16x8*>(
            reinterpret_cast<const char*>(xt) + (pl << 7) +
            ((qk ^ (pl & 7)) << 4));
        #pragma unroll
        for (int i = 0; i < 4; ++i)
          acc[i][j] = __builtin_amdgcn_mfma_f32_16x16x32_bf16(
              abuf[cur][i][kh], bv, acc[i][j], 0, 0, 0);
      }
    }
    __builtin_amdgcn_s_setprio(0);
  }

  // epilogue: D col = m (px), row = q*4+r (co in group); co = i*16 + q*4 + r
  const float* bp = bias + b * CO;
  float* ob = out + ((size_t)(b * CO) << 14) + (size_t)((y0 + ty0) * WW + x0 + m);
  #pragma unroll
  for (int i = 0; i < 4; ++i)
    #pragma unroll
    for (int j = 0; j < 2; ++j)
      #pragma unroll
      for (int r = 0; r < 4; ++r) {
        const int co = i * 16 + q * 4 + r;
        float v = acc[i][j][r] + bp[co];
        ob[((size_t)co << 14) + j * WW] = fmaxf(v, 0.f);
      }
}

// ---------------- fallback conv (v4, reads raw x) ----------------
__global__ __launch_bounds__(512, 4)
void conv_fb(const float* __restrict__ x, const bf16* __restrict__ wt2,
             const float* __restrict__ bias, float* __restrict__ out) {
  __shared__ __align__(16) bf16 xt[NPL * 64];

  const int id = (blockIdx.x & 7) * 128 + (blockIdx.x >> 3);
  const int b = id >> 6;
  const int x0 = (id & 7) * TS;
  const int y0 = ((id >> 3) & 7) * TS;

  const int tid = threadIdx.x;
  const int lane = tid & 63;
  const int wv = tid >> 6;
  const int m = lane & 15;
  const int q = lane >> 4;

  const char* wbase = (const char*)wt2 + (size_t)b * 73728 + lane * 16;

  bf16x8 abuf[2][4][2];
  #pragma unroll
  for (int i = 0; i < 4; ++i)
    #pragma unroll
    for (int kh = 0; kh < 2; ++kh)
      abuf[0][i][kh] =
          *reinterpret_cast<const bf16x8*>(wbase + (i * 2 + kh) * 1024);

  const float* xb = x + ((size_t)b << 20);
  for (int t = 0; t < 6; ++t) {
    const int it = min(tid + t * 512, NPL * 8 - 1);
    const int cig = ((it >> 2) * 810) >> 16;
    const int pl = it - cig * 324;
    const int py = (pl * 57) >> 10;
    const int px = pl - py * 18;
    int gy = y0 + py - 1, gx = x0 + px - 1;
    const bool inb = ((unsigned)gy < (unsigned)HH) & ((unsigned)gx < (unsigned)WW);
    gy = min(max(gy, 0), HH - 1);
    gx = min(max(gx, 0), WW - 1);
    const float* src = xb + ((size_t)cig << 17) + (gy << 7) + gx;
    bf16x8 v8;
    #pragma unroll
    for (int j = 0; j < 8; ++j)
      v8[j] = inb ? (bf16)src[(size_t)j << 14] : (bf16)0.f;
    if (!(t == 5 && tid >= NPL * 8 - 5 * 512))
      *reinterpret_cast<bf16x8*>(reinterpret_cast<char*>(xt) + (pl << 7) +
                                 ((cig ^ (pl & 7)) << 4)) = v8;
  }

  f32x4 acc[4][2];
  #pragma unroll
  for (int i = 0; i < 4; ++i) {
    acc[i][0] = (f32x4){0.f, 0.f, 0.f, 0.f};
    acc[i][1] = (f32x4){0.f, 0.f, 0.f, 0.f};
  }
  const int ty0 = wv * 2;
  __syncthreads();

  #pragma unroll
  for (int tap = 0; tap < 9; ++tap) {
    const int cur = tap & 1, nxt = cur ^ 1;
    if (tap < 8) {
      const char* wt_n = wbase + (tap + 1) * 8192;
      #pragma unroll
      for (int i = 0; i < 4; ++i)
        #pragma unroll
        for (int kh = 0; kh < 2; ++kh)
          abuf[nxt][i][kh] =
              *reinterpret_cast<const bf16x8*>(wt_n + (i * 2 + kh) * 1024);
    }
    const int dy = (tap * 11) >> 5;
    const int dx = tap - dy * 3;
    const int plb = (ty0 + dy) * 18 + dx + m;
    __builtin_amdgcn_s_setprio(1);
    #pragma unroll
    for (int kh = 0; kh < 2; ++kh) {
      const int qk = q + kh * 4;
      #pragma unroll
      for (int j = 0; j < 2; ++j) {
        const int pl = plb + j * 18;
        const bf16x8 bv = *reinterpret_cast<const bf16x8*>(
            reinterpret_cast<const char*>(xt) + (pl << 7) +
            ((qk ^ (pl & 7)) << 4));
        #pragma unroll
        for (int i = 0; i < 4; ++i)
          acc[i][j] = __builtin_amdgcn_mfma_f32_16x16x32_bf16(
              abuf[cur][i][kh], bv, acc[i][j], 0, 0, 0);
      }
    }
    __builtin_amdgcn_s_setprio(0);
  }

  const float* bp = bias + b * CO;
  float* ob = out + ((size_t)(b * CO) << 14) + (size_t)((y0 + ty0) * WW + x0 + m);
  #pragma unroll
  for (int i = 0; i < 4; ++i)
    #pragma unroll
    for (int j = 0; j < 2; ++j)
      #pragma unroll
      for (int r = 0; r < 4; ++r) {
        const int co = i * 16 + q * 4 + r;
        float v = acc[i][j][r] + bp[co];
        ob[((size_t)co << 14) + j * WW] = fmaxf(v, 0.f);
      }
}

extern "C" void kernel_launch(void* const* d_in, const int* in_sizes, int n_in,
                              void* d_out, int out_size, void* d_ws,
                              size_t ws_size, hipStream_t stream) {
  const float* x = (const float*)d_in[0];
  const float* z = (const float*)d_in[1];
  const float* W0 = (const float*)d_in[2];
  const float* b0 = (const float*)d_in[3];
  const float* W1 = (const float*)d_in[4];
  const float* b1 = (const float*)d_in[5];
  const float* W2 = (const float*)d_in[6];
  const float* b2 = (const float*)d_in[7];
  float* out = (float*)d_out;

  bf16* wt2 = (bf16*)d_ws;
  float* biases = (float*)((char*)d_ws + WT2_BYTES);
  bf16* xh = (bf16*)((char*)d_ws + WT2_BYTES + BIAS_BYTES);

  if (ws_size >= WS_NEED) {
    hipLaunchKernelGGL(prep_kernel, dim3(145 + NB * XHW), dim3(256), 0, stream,
                       x, z, W0, b0, W1, b1, W2, b2, wt2, biases, xh);
    hipLaunchKernelGGL(conv_kernel, dim3(1024), dim3(512), 0, stream, xh, wt2,
                       biases, out);
  } else { // workspace too small: v4 path
    hipLaunchKernelGGL(prep_kernel, dim3(145), dim3(256), 0, stream, x, z, W0,
                       b0, W1, b1, W2, b2, wt2, biases, xh);
    hipLaunchKernelGGL(conv_fb, dim3(1024), dim3(512), 0, stream, x, wt2,
                       biases, out);
  }
}

// Round 7
// 159.034 us; speedup vs baseline: 1.2066x; 1.0273x over previous
//
#include <hip/hip_runtime.h>

// AdaptiveConv2d v8: conv (v6) unchanged. Prep transpose restructured for
// latency tolerance: lane=ci streaming reads (8x float4/thread, full-line
// consumption), two-row software pipeline per block (row1 loads in flight
// under row0 convert+store), double-buffered LDS, conflict-free b16 LDS
// writes (64 lanes cover 128B = 2 lanes/bank). Store path = v7 verified.

typedef __bf16 bf16;
typedef __bf16 bf16x8 __attribute__((ext_vector_type(8)));
typedef float f32x4 __attribute__((ext_vector_type(4)));

#define NB 16
#define CI 64
#define CO 64
#define HH 128
#define WW 128
#define TS 16
#define HALO 18           // TS + 2
#define NPL (HALO * HALO) // 324 halo pixels
#define NKW 36864         // CO*CI*9
#define NROWS 36928
#define XHW 130           // bordered NHWC width/height
#define WT2_BYTES ((size_t)NB * 9 * 4096 * 2)       // 1,179,648
#define BIAS_BYTES 4096
#define XH_BYTES ((size_t)NB * XHW * XHW * CI * 2)  // 34,611,200
#define WS_NEED (WT2_BYTES + BIAS_BYTES + XH_BYTES)

typedef const __attribute__((address_space(1))) void* gas_ptr;
typedef __attribute__((address_space(3))) void* las_ptr;

// ---------------- prep: hypernetwork + x transpose ----------------
// blocks 0..144: hyper (thread owns one W2 row, loops 16 samples; kernel
// rows land pre-swizzled for the conv A-fragment:
//   elem off = ((b*9+tap)*8 + g*2 + kh)*512 + (q*16+m)*8 + j ).
// blocks 145+: one (sample, row-pair) of xh [16][130][130][64] bf16 with
// zero border. Pipeline: load r0 -> issue r1 loads -> cvt/LDS r0 -> bar ->
// store r0 (overlaps r1 latency) -> cvt/LDS r1 -> bar -> store r1.
__global__ __launch_bounds__(256, 4)
void prep_kernel(const float* __restrict__ x, const float* __restrict__ z,
                 const float* __restrict__ W0, const float* __restrict__ b0,
                 const float* __restrict__ W1, const float* __restrict__ b1,
                 const float* __restrict__ W2, const float* __restrict__ b2,
                 bf16* __restrict__ wt2, float* __restrict__ biases,
                 bf16* __restrict__ xh) {
  const int tid = threadIdx.x;
  if (blockIdx.x < 145) {
    __shared__ float h1s[NB][30];
    if (tid < NB) {
      float h0[20];
      #pragma unroll
      for (int i = 0; i < 20; ++i) {
        float s = b0[i];
        #pragma unroll
        for (int j = 0; j < 16; ++j) s += W0[i * 16 + j] * z[tid * 16 + j];
        h0[i] = fmaxf(s, 0.f);
      }
      #pragma unroll
      for (int i = 0; i < 30; ++i) {
        float s = b1[i];
        #pragma unroll
        for (int j = 0; j < 20; ++j) s += W1[i * 20 + j] * h0[j];
        h1s[tid][i] = fmaxf(s, 0.f);
      }
    }
    __syncthreads();
    const int r = blockIdx.x * 256 + tid;
    if (r >= NROWS) return;
    float w2r[30];
    #pragma unroll
    for (int j = 0; j < 30; ++j) w2r[j] = W2[r * 30 + j];
    const float bb = b2[r];
    const bool isk = r < NKW;
    size_t base = 0;
    if (isk) {
      const int co = r / 576;
      const int rem = r - co * 576;
      const int ci = rem / 9;
      const int tap = rem - ci * 9;
      const int g = co >> 4, mm = co & 15;
      const int kh = ci >> 5, qq = (ci >> 3) & 3, jj = ci & 7;
      base = (size_t)(tap * 8 + g * 2 + kh) * 512 + (size_t)(qq * 16 + mm) * 8 + jj;
    }
    for (int b = 0; b < NB; ++b) {
      float s = bb;
      #pragma unroll
      for (int j = 0; j < 30; ++j) s += w2r[j] * h1s[b][j];
      s = fmaxf(s, 0.f);
      if (isk)
        wt2[(size_t)b * (9 * 4096) + base] = (bf16)s;
      else
        biases[b * CO + (r - NKW)] = s;
    }
    return;
  }

  // ---- transpose blocks: one (b, row-pair yp0, yp0+1) ----
  const int bi = blockIdx.x - 145;
  const int b = bi / 65;
  const int pr = bi - b * 65;
  const int yp0 = pr * 2;

  const int w = tid >> 6, lane = tid & 63;
  const int px0 = w * 32;

  bf16* row0 = xh + ((size_t)(b * XHW + yp0)) * XHW * CI;
  bf16* row1 = row0 + XHW * CI;

  __shared__ __align__(16) bf16 xls[2][128 * 64]; // 2 x 16 KB

  const bool z0 = (yp0 == 0);
  const bool z1 = (yp0 + 1 == XHW - 1);
  const float* xsrc = x + (((size_t)b * CI + lane) << 14) + px0;

  // issue ALL loads for both rows before any use (16 float4 in flight)
  float v0[32], v1[32];
  if (!z0) {
    const float* s0 = xsrc + ((size_t)(yp0 - 1) << 7);
    #pragma unroll
    for (int j = 0; j < 8; ++j)
      *reinterpret_cast<f32x4*>(&v0[4 * j]) =
          *reinterpret_cast<const f32x4*>(s0 + 4 * j);
  }
  if (!z1) {
    const float* s1 = xsrc + ((size_t)yp0 << 7);
    #pragma unroll
    for (int j = 0; j < 8; ++j)
      *reinterpret_cast<f32x4*>(&v1[4 * j]) =
          *reinterpret_cast<const f32x4*>(s1 + 4 * j);
  }

  const int gq = lane >> 3;        // ci octet
  const int bo = (lane & 7) << 1;  // byte within 16B granule
  const bf16x8 zero8 = {};

  // row 0: convert + conflict-free b16 LDS writes (octet g -> slot g^(px&7))
  if (!z0) {
    #pragma unroll
    for (int p = 0; p < 32; ++p) {
      const int pxl = px0 + p;
      *reinterpret_cast<bf16*>(reinterpret_cast<char*>(xls[0]) + (pxl << 7) +
                               ((gq ^ (pxl & 7)) << 4) + bo) = (bf16)v0[p];
    }
  }
  __syncthreads();
  // store row 0 (row1 loads still in flight underneath)
  #pragma unroll
  for (int k = 0; k < 5; ++k) {
    const int it = k * 256 + tid;
    if (it >= XHW * 8) break; // k=4: only tid<16
    const int pxp = it >> 3, gr = it & 7;
    bf16x8 vv = zero8;
    if (!z0 && pxp >= 1 && pxp <= 128) {
      const int px = pxp - 1;
      vv = *reinterpret_cast<const bf16x8*>(
          reinterpret_cast<const char*>(xls[0]) + (px << 7) +
          ((gr ^ (px & 7)) << 4));
    }
    *reinterpret_cast<bf16x8*>(row0 + it * 8) = vv;
  }

  // row 1: convert + LDS (independent buffer; no barrier vs row0 store)
  if (!z1) {
    #pragma unroll
    for (int p = 0; p < 32; ++p) {
      const int pxl = px0 + p;
      *reinterpret_cast<bf16*>(reinterpret_cast<char*>(xls[1]) + (pxl << 7) +
                               ((gq ^ (pxl & 7)) << 4) + bo) = (bf16)v1[p];
    }
  }
  __syncthreads();
  #pragma unroll
  for (int k = 0; k < 5; ++k) {
    const int it = k * 256 + tid;
    if (it >= XHW * 8) break;
    const int pxp = it >> 3, gr = it & 7;
    bf16x8 vv = zero8;
    if (!z1 && pxp >= 1 && pxp <= 128) {
      const int px = pxp - 1;
      vv = *reinterpret_cast<const bf16x8*>(
          reinterpret_cast<const char*>(xls[1]) + (px << 7) +
          ((gr ^ (px & 7)) << 4));
    }
    *reinterpret_cast<bf16x8*>(row1 + it * 8) = vv;
  }
}

// ---------------- conv v6 (implicit GEMM, bf16 MFMA) — unchanged ----------------
// 1D grid 1024, XCD-swizzled (XCD k <- 2 complete samples). Block: 512
// thr = 8 waves, 1 sample x 16x16 px x all 64 co; wave wv rows {2wv,2wv+1},
// acc[4 co-groups][2 rows]. x tile: global_load_lds from xh, LDS granule
// e=(pl,g) sourced from xh granule (pl, g^(pl&7)) -> linear dest, swizzled
// conflict-free reads. Weights: double-buffered registers. ONE barrier.
__global__ __launch_bounds__(512, 4)
void conv_kernel(const bf16* __restrict__ xh, const bf16* __restrict__ wt2,
                 const float* __restrict__ bias, float* __restrict__ out) {
  __shared__ __align__(16) bf16 xt[2624 * 8]; // 41,984 B (2592 + tail pad)

  const int id = (blockIdx.x & 7) * 128 + (blockIdx.x >> 3); // bijective
  const int b = id >> 6;
  const int x0 = (id & 7) * TS;
  const int y0 = ((id >> 3) & 7) * TS;

  const int tid = threadIdx.x;
  const int lane = tid & 63;
  const int wv = tid >> 6; // 0..7
  const int m = lane & 15;
  const int q = lane >> 4;

  const char* wbase = (const char*)wt2 + (size_t)b * 73728 + lane * 16;

  // ---- prefetch tap-0 A-fragments (first into the vmem queue) ----
  bf16x8 abuf[2][4][2];
  #pragma unroll
  for (int i = 0; i < 4; ++i)
    #pragma unroll
    for (int kh = 0; kh < 2; ++kh)
      abuf[0][i][kh] =
          *reinterpret_cast<const bf16x8*>(wbase + (i * 2 + kh) * 1024);

  // ---- stage x tile: 2592 granules of 16B via global_load_lds ----
  {
    const char* xb =
        (const char*)xh + (((size_t)(b * XHW + y0)) * XHW + x0) * 128;
    #pragma unroll
    for (int k = 0; k < 5; ++k) {
      const int e = k * 512 + tid;
      const int pl = e >> 3;
      const int gs = (e & 7) ^ (pl & 7);
      const int py = (pl * 57) >> 10; // pl/18, exact for pl < 512
      const int px = pl - py * 18;
      __builtin_amdgcn_global_load_lds(
          (gas_ptr)(xb + ((py * XHW + px) << 7) + (gs << 4)),
          (las_ptr)((char*)xt + ((k * 512 + wv * 64) << 4)), 16, 0, 0);
    }
    if (wv == 0) { // tail: granules 2560..2591 (+32 clamped dups into pad)
      const int esrc = min(2560 + lane, 2591);
      const int pl = esrc >> 3;
      const int gs = (esrc & 7) ^ (pl & 7);
      const int py = (pl * 57) >> 10;
      const int px = pl - py * 18;
      __builtin_amdgcn_global_load_lds(
          (gas_ptr)(xb + ((py * XHW + px) << 7) + (gs << 4)),
          (las_ptr)((char*)xt + (2560 << 4)), 16, 0, 0);
    }
  }

  f32x4 acc[4][2];
  #pragma unroll
  for (int i = 0; i < 4; ++i) {
    acc[i][0] = (f32x4){0.f, 0.f, 0.f, 0.f};
    acc[i][1] = (f32x4){0.f, 0.f, 0.f, 0.f};
  }

  const int ty0 = wv * 2;

  __syncthreads(); // staging drained (vmcnt(0) implicit before barrier)

  #pragma unroll
  for (int tap = 0; tap < 9; ++tap) {
    const int cur = tap & 1, nxt = cur ^ 1; // compile-time after unroll
    if (tap < 8) { // prefetch next tap's A-frags; overlaps this tap's MFMAs
      const char* wt_n = wbase + (tap + 1) * 8192;
      #pragma unroll
      for (int i = 0; i < 4; ++i)
        #pragma unroll
        for (int kh = 0; kh < 2; ++kh)
          abuf[nxt][i][kh] =
              *reinterpret_cast<const bf16x8*>(wt_n + (i * 2 + kh) * 1024);
    }
    const int dy = (tap * 11) >> 5; // tap/3
    const int dx = tap - dy * 3;
    const int plb = (ty0 + dy) * 18 + dx + m;
    __builtin_amdgcn_s_setprio(1);
    #pragma unroll
    for (int kh = 0; kh < 2; ++kh) {
      const int qk = q + kh * 4;
      #pragma unroll
      for (int j = 0; j < 2; ++j) {
        const int pl = plb + j * 18;
        const bf16x8 bv = *reinterpret_cast<const bf16x8*>(
            reinterpret_cast<const char*>(xt) + (pl << 7) +
            ((qk ^ (pl & 7)) << 4));
        #pragma unroll
        for (int i = 0; i < 4; ++i)
          acc[i][j] = __builtin_amdgcn_mfma_f32_16x16x32_bf16(
              abuf[cur][i][kh], bv, acc[i][j], 0, 0, 0);
      }
    }
    __builtin_amdgcn_s_setprio(0);
  }

  // epilogue: D col = m (px), row = q*4+r (co in group); co = i*16 + q*4 + r
  const float* bp = bias + b * CO;
  float* ob = out + ((size_t)(b * CO) << 14) + (size_t)((y0 + ty0) * WW + x0 + m);
  #pragma unroll
  for (int i = 0; i < 4; ++i)
    #pragma unroll
    for (int j = 0; j < 2; ++j)
      #pragma unroll
      for (int r = 0; r < 4; ++r) {
        const int co = i * 16 + q * 4 + r;
        float v = acc[i][j][r] + bp[co];
        ob[((size_t)co << 14) + j * WW] = fmaxf(v, 0.f);
      }
}

// ---------------- fallback conv (v4, reads raw x) ----------------
__global__ __launch_bounds__(512, 4)
void conv_fb(const float* __restrict__ x, const bf16* __restrict__ wt2,
             const float* __restrict__ bias, float* __restrict__ out) {
  __shared__ __align__(16) bf16 xt[NPL * 64];

  const int id = (blockIdx.x & 7) * 128 + (blockIdx.x >> 3);
  const int b = id >> 6;
  const int x0 = (id & 7) * TS;
  const int y0 = ((id >> 3) & 7) * TS;

  const int tid = threadIdx.x;
  const int lane = tid & 63;
  const int wv = tid >> 6;
  const int m = lane & 15;
  const int q = lane >> 4;

  const char* wbase = (const char*)wt2 + (size_t)b * 73728 + lane * 16;

  bf16x8 abuf[2][4][2];
  #pragma unroll
  for (int i = 0; i < 4; ++i)
    #pragma unroll
    for (int kh = 0; kh < 2; ++kh)
      abuf[0][i][kh] =
          *reinterpret_cast<const bf16x8*>(wbase + (i * 2 + kh) * 1024);

  const float* xb = x + ((size_t)b << 20);
  for (int t = 0; t < 6; ++t) {
    const int it = min(tid + t * 512, NPL * 8 - 1);
    const int cig = ((it >> 2) * 810) >> 16;
    const int pl = it - cig * 324;
    const int py = (pl * 57) >> 10;
    const int px = pl - py * 18;
    int gy = y0 + py - 1, gx = x0 + px - 1;
    const bool inb = ((unsigned)gy < (unsigned)HH) & ((unsigned)gx < (unsigned)WW);
    gy = min(max(gy, 0), HH - 1);
    gx = min(max(gx, 0), WW - 1);
    const float* src = xb + ((size_t)cig << 17) + (gy << 7) + gx;
    bf16x8 v8;
    #pragma unroll
    for (int j = 0; j < 8; ++j)
      v8[j] = inb ? (bf16)src[(size_t)j << 14] : (bf16)0.f;
    if (!(t == 5 && tid >= NPL * 8 - 5 * 512))
      *reinterpret_cast<bf16x8*>(reinterpret_cast<char*>(xt) + (pl << 7) +
                                 ((cig ^ (pl & 7)) << 4)) = v8;
  }

  f32x4 acc[4][2];
  #pragma unroll
  for (int i = 0; i < 4; ++i) {
    acc[i][0] = (f32x4){0.f, 0.f, 0.f, 0.f};
    acc[i][1] = (f32x4){0.f, 0.f, 0.f, 0.f};
  }
  const int ty0 = wv * 2;
  __syncthreads();

  #pragma unroll
  for (int tap = 0; tap < 9; ++tap) {
    const int cur = tap & 1, nxt = cur ^ 1;
    if (tap < 8) {
      const char* wt_n = wbase + (tap + 1) * 8192;
      #pragma unroll
      for (int i = 0; i < 4; ++i)
        #pragma unroll
        for (int kh = 0; kh < 2; ++kh)
          abuf[nxt][i][kh] =
              *reinterpret_cast<const bf16x8*>(wt_n + (i * 2 + kh) * 1024);
    }
    const int dy = (tap * 11) >> 5;
    const int dx = tap - dy * 3;
    const int plb = (ty0 + dy) * 18 + dx + m;
    __builtin_amdgcn_s_setprio(1);
    #pragma unroll
    for (int kh = 0; kh < 2; ++kh) {
      const int qk = q + kh * 4;
      #pragma unroll
      for (int j = 0; j < 2; ++j) {
        const int pl = plb + j * 18;
        const bf16x8 bv = *reinterpret_cast<const bf16x8*>(
            reinterpret_cast<const char*>(xt) + (pl << 7) +
            ((qk ^ (pl & 7)) << 4));
        #pragma unroll
        for (int i = 0; i < 4; ++i)
          acc[i][j] = __builtin_amdgcn_mfma_f32_16x16x32_bf16(
              abuf[cur][i][kh], bv, acc[i][j], 0, 0, 0);
      }
    }
    __builtin_amdgcn_s_setprio(0);
  }

  const float* bp = bias + b * CO;
  float* ob = out + ((size_t)(b * CO) << 14) + (size_t)((y0 + ty0) * WW + x0 + m);
  #pragma unroll
  for (int i = 0; i < 4; ++i)
    #pragma unroll
    for (int j = 0; j < 2; ++j)
      #pragma unroll
      for (int r = 0; r < 4; ++r) {
        const int co = i * 16 + q * 4 + r;
        float v = acc[i][j][r] + bp[co];
        ob[((size_t)co << 14) + j * WW] = fmaxf(v, 0.f);
      }
}

extern "C" void kernel_launch(void* const* d_in, const int* in_sizes, int n_in,
                              void* d_out, int out_size, void* d_ws,
                              size_t ws_size, hipStream_t stream) {
  const float* x = (const float*)d_in[0];
  const float* z = (const float*)d_in[1];
  const float* W0 = (const float*)d_in[2];
  const float* b0 = (const float*)d_in[3];
  const float* W1 = (const float*)d_in[4];
  const float* b1 = (const float*)d_in[5];
  const float* W2 = (const float*)d_in[6];
  const float* b2 = (const float*)d_in[7];
  float* out = (float*)d_out;

  bf16* wt2 = (bf16*)d_ws;
  float* biases = (float*)((char*)d_ws + WT2_BYTES);
  bf16* xh = (bf16*)((char*)d_ws + WT2_BYTES + BIAS_BYTES);

  if (ws_size >= WS_NEED) {
    hipLaunchKernelGGL(prep_kernel, dim3(145 + NB * 65), dim3(256), 0, stream,
                       x, z, W0, b0, W1, b1, W2, b2, wt2, biases, xh);
    hipLaunchKernelGGL(conv_kernel, dim3(1024), dim3(512), 0, stream, xh, wt2,
                       biases, out);
  } else { // workspace too small: v4 path
    hipLaunchKernelGGL(prep_kernel, dim3(145), dim3(256), 0, stream, x, z, W0,
                       b0, W1, b1, W2, b2, wt2, biases, xh);
    hipLaunchKernelGGL(conv_fb, dim3(1024), dim3(512), 0, stream, x, wt2,
                       biases, out);
  }
}